// Round 13
// baseline (435.591 us; speedup 1.0000x reference)
//
#include <hip/hip_runtime.h>
#include <hip/hip_bf16.h>
#include <math.h>
#include <stdint.h>

// ---- problem constants ----
#define B_    4
#define S_    2048
#define D_    768
#define H_    8
#define HD_   96
#define EXPD_ 3072
#define MSZ   8192   // B*S

#define QSCALE 0.14724439f   // HD^-0.5 * log2(e), folded into Q at QKV epilogue
#define M0_    12.0f         // fixed softmax exponent offset

typedef __bf16 bf16;
typedef __bf16 bf16x4 __attribute__((ext_vector_type(4)));
typedef __bf16 bf16x8 __attribute__((ext_vector_type(8)));
typedef float  f32x4  __attribute__((ext_vector_type(4)));
typedef float  f32x16 __attribute__((ext_vector_type(16)));

typedef __attribute__((address_space(1))) const uint32_t gu32;
typedef __attribute__((address_space(3))) uint32_t lu32;

__device__ __forceinline__ void async_copy16(const void* g, void* l) {
    __builtin_amdgcn_global_load_lds((gu32*)g, (lu32*)l, 16, 0, 0);
}

template<int N> __device__ __forceinline__ void vm_wait() {
    if constexpr (N == 0)      asm volatile("s_waitcnt vmcnt(0)" ::: "memory");
    else if constexpr (N == 3) asm volatile("s_waitcnt vmcnt(3)" ::: "memory");
    else if constexpr (N == 4) asm volatile("s_waitcnt vmcnt(4)" ::: "memory");
    else static_assert(N == 0 || N == 3 || N == 4, "unsupported vmcnt");
}

// GELU (tanh form), computed via exp2: tanh(z) = (e^2z - 1)/(e^2z + 1)
// => gelu = x - x/(e^2z + 1).  Algebraically identical to the tanhf form
// but ~9 VALU ops vs the ~16-op OCML tanhf; saturates correctly at both
// tails (x - 0 = x for z >> 0; x - x = 0 for z << 0) with no inf*0.
__device__ __forceinline__ float gelu_f(float x) {
    float x3 = x * x * x;
    float z  = 0.7978845608028654f * (x + 0.044715f * x3);
    float t  = exp2f(2.8853900817779268f * z);   // e^{2z}
    return x - x / (t + 1.0f);
}

// Runtime dtype sniff: f32 buffer read as bf16 at even indices yields random
// exponents -> some |v|>=1e3 among 64 samples w.p. ~1. bf16 weights never trip.
__device__ __forceinline__ bool sniff_f32(const void* p) {
    const bf16* pb = (const bf16*)p;
    float v = (float)pb[2 * (threadIdx.x & 63)];
    bool big = !(fabsf(v) < 1000.0f);
    return __any(big) != 0;
}

__device__ __forceinline__ float dynld(const void* p, size_t i, bool f32in) {
    return f32in ? ((const float*)p)[i] : (float)((const bf16*)p)[i];
}

// Transpose 64x64 tile helper
__device__ __forceinline__ void transpose_tile(
    const void* __restrict__ src, bf16* __restrict__ dst, int R, int C,
    int r0, int c0, bool f32in)
{
    __shared__ bf16 t[64][65];
    const int tx = threadIdx.x & 63, ty = threadIdx.x >> 6;
#pragma unroll
    for (int i = 0; i < 16; ++i) {
        int rr = ty + i * 4;
        t[rr][tx] = (bf16)dynld(src, (size_t)(r0 + rr) * C + c0 + tx, f32in);
    }
    __syncthreads();
#pragma unroll
    for (int i = 0; i < 16; ++i) {
        int cc = ty + i * 4;
        dst[(size_t)(c0 + cc) * R + r0 + tx] = t[tx][cc];
    }
}

// Merged prep: cast x->bf16 (nCast blocks, 8 el/thread) + transpose
// Wq/Wk/Wv -> qkvT (432 blocks).  Validated R12: QKV unchanged (R8's
// regression was mlpT-in-d_out L2 eviction, not the merge).
__global__ __launch_bounds__(256) void prep_kernel(
    const void* __restrict__ x, bf16* __restrict__ xb, int nCast,
    const void* __restrict__ Wq, const void* __restrict__ Wk, const void* __restrict__ Wv,
    bf16* __restrict__ qkvT)
{
    int id = blockIdx.x;
    if (id < nCast) {
        const bool f32in = sniff_f32(x);
        size_t i = ((size_t)id * 256 + threadIdx.x) * 8;
        if (f32in) {
            f32x4 a = *(const f32x4*)((const float*)x + i);
            f32x4 b = *(const f32x4*)((const float*)x + i + 4);
            bf16x8 r;
#pragma unroll
            for (int e = 0; e < 4; ++e) { r[e] = (bf16)a[e]; r[e + 4] = (bf16)b[e]; }
            *(bf16x8*)(xb + i) = r;
        } else {
            *(bf16x8*)(xb + i) = *(const bf16x8*)((const bf16*)x + i);
        }
        return;
    }
    id -= nCast;
    int z = id / 144, rem = id - z * 144;
    const void* src = z == 0 ? Wq : (z == 1 ? Wk : Wv);
    const bool f32in = sniff_f32(src);
    transpose_tile(src, qkvT + (size_t)z * D_ * D_, D_, D_,
                   (rem / 12) * 64, (rem % 12) * 64, f32in);
}

#define MODE_QKV  0   // fused QKV: Q(*QSCALE),K -> [bh][S][HD]; V -> [bh][HD][S]
#define MODE_RES  1   // out bf16 = c + bias(if boff>=0) + res
#define MODE_GELU 2   // out bf16 = gelu(c + bias)

// 32x32x16-MFMA GEMM.  v6: 1-BARRIER-PER-STEP (T3-min template).
// BK=32 double-buffer, one vmcnt(0)+barrier per step (staging is
// L2-resident -> the drain is near-free), T2 XOR swizzle, setprio around
// the MFMA cluster.  16 KB/buffer (BN=128) -> 32 KB LDS -> 5 blocks/CU.
// Loop: stage(t+1) early; compute(t); vmcnt(0); s_barrier.
// Hazards: stage(t) drained by prev iter's vmcnt(0)+barrier before any
// wave's ds_read(t); stage(t+1) overwrites the buffer last read at
// compute(t-1), separated by the same barrier.
// C = A(MxK, row-stride lda) @ Bt(NxK, row-stride ldb)^T + bias[boff+n]
// (boff<0: none). Tile 128xBN, 4 waves. K must be a multiple of 64.
// XCD-aware 1-D grid decode (m fastest within per-XCD stripe).
template<int MODE, bool ADYN, bool RESDYN, int BN>
__global__ __launch_bounds__(256) void gemm2_kernel(
    const void* __restrict__ A, const bf16* __restrict__ Bt,
    const void* __restrict__ b0, const void* __restrict__ b1, const void* __restrict__ b2,
    const void* __restrict__ res, bf16* __restrict__ out,
    int M, int N, int K, int lda, int ldb, int boff, int mstripe,
    const void* __restrict__ sniffp)
{
    constexpr int WN   = BN / 2;
    constexpr int NJ32 = WN / 32;
    constexpr int ABUF = 4096;        // A panel: 128x32 el
    constexpr int BBUF = BN * 32;     // B panel: BNx32 el
    constexpr int BUF  = ABUF + BBUF;
    __shared__ __align__(16) bf16 Sh[2 * BUF];   // >= 8192 el for epilogue

    const bool f32in = sniff_f32(sniffp);
    const int tid  = threadIdx.x;
    const int w    = tid >> 6;
    const int lane = tid & 63;
    const int l32  = lane & 31;
    const int kh   = lane >> 5;     // k-half within a 16-wide mfma step
    const int wr   = w >> 1, wc = w & 1;

    // XCD-aware block decode (m-fast within stripe)
    const int lin  = blockIdx.x;
    const int xcd  = lin & 7;
    const int q    = lin >> 3;
    const int nb   = q / mstripe;
    const int mbin = q - nb * mstripe;
    const int m0   = (xcd * mstripe + mbin) * 128;
    const int n0   = nb * BN;

    const int rsub = lane >> 2;
    // swizzled global k-chunk for this lane's staging slot (T2, write side)
    const int cswz = (((lane & 3) ^ ((rsub >> 1) & 3))) * 8;
    // read-side XOR term (row bits 1..2; chunk bases are multiples of 8)
    const int xh   = (l32 >> 1) & 3;

    f32x16 acc[2][NJ32];
#pragma unroll
    for (int i = 0; i < 2; ++i)
#pragma unroll
        for (int j = 0; j < NJ32; ++j)
#pragma unroll
            for (int e = 0; e < 16; ++e) acc[i][j][e] = 0.f;

    const bf16*  Abf = (const bf16*)A;
    const float* Af  = (const float*)A;

    // stage K-tile at element offset k0 into buffer bsel (async bf16 path)
    auto stage = [&](int k0, int bsel) {
        bf16* As = Sh + bsel * BUF;
        bf16* Bs = As + ABUF;
#pragma unroll
        for (int p = 0; p < 2; ++p) {
            int row = p * 64 + w * 16;      // wave-uniform base row
            async_copy16(Abf + (size_t)(m0 + row + rsub) * lda + k0 + cswz,
                         &As[row * 32]);
        }
#pragma unroll
        for (int p = 0; p < BN / 64; ++p) {
            int row = p * 64 + w * 16;
            async_copy16(Bt + (size_t)(n0 + row + rsub) * ldb + k0 + cswz,
                         &Bs[row * 32]);
        }
    };

    // ds_read fragments (swizzled) + clustered MFMA for one K-tile
    auto compute = [&](int bsel) {
        const bf16* As = Sh + bsel * BUF;
        const bf16* Bs = As + ABUF;
        bf16x8 af[2][2], bfv[NJ32][2];
#pragma unroll
        for (int i = 0; i < 2; ++i)
#pragma unroll
            for (int ks = 0; ks < 2; ++ks)
                af[i][ks] = *(const bf16x8*)(&As[(wr * 64 + i * 32 + l32) * 32
                                                + (((ks * 2 + kh) ^ xh) * 8)]);
#pragma unroll
        for (int j = 0; j < NJ32; ++j)
#pragma unroll
            for (int ks = 0; ks < 2; ++ks)
                bfv[j][ks] = *(const bf16x8*)(&Bs[(wc * WN + j * 32 + l32) * 32
                                                  + (((ks * 2 + kh) ^ xh) * 8)]);
        asm volatile("s_waitcnt lgkmcnt(0)" ::: "memory");
        __builtin_amdgcn_sched_barrier(0);
        __builtin_amdgcn_s_setprio(1);
#pragma unroll
        for (int i = 0; i < 2; ++i)
#pragma unroll
            for (int j = 0; j < NJ32; ++j)
#pragma unroll
                for (int ks = 0; ks < 2; ++ks)
                    acc[i][j] = __builtin_amdgcn_mfma_f32_32x32x16_bf16(af[i][ks], bfv[j][ks], acc[i][j], 0, 0, 0);
        __builtin_amdgcn_s_setprio(0);
    };

    const int nk = K >> 5;
    if constexpr (ADYN) {
        // legacy drain loop (f32-A fallback; LDS writes need full drains)
        auto stage_adyn = [&](int k0, int bsel) {
            bf16* As = Sh + bsel * BUF;
            bf16* Bs = As + ABUF;
            if (f32in) {
#pragma unroll
                for (int p = 0; p < 2; ++p) {
                    int row = p * 64 + w * 16 + rsub;
                    const float* sp = Af + (size_t)(m0 + row) * lda + k0 + cswz;
                    f32x4 u0 = *(const f32x4*)sp;
                    f32x4 u1 = *(const f32x4*)(sp + 4);
                    bf16x8 v;
#pragma unroll
                    for (int e = 0; e < 4; ++e) { v[e] = (bf16)u0[e]; v[e + 4] = (bf16)u1[e]; }
                    *(bf16x8*)(&As[row * 32 + (lane & 3) * 8]) = v;
                }
            } else {
#pragma unroll
                for (int p = 0; p < 2; ++p) {
                    int row = p * 64 + w * 16;
                    async_copy16(Abf + (size_t)(m0 + row + rsub) * lda + k0 + cswz,
                                 &As[row * 32]);
                }
            }
#pragma unroll
            for (int p = 0; p < BN / 64; ++p) {
                int row = p * 64 + w * 16;
                async_copy16(Bt + (size_t)(n0 + row + rsub) * ldb + k0 + cswz,
                             &Bs[row * 32]);
            }
        };
        stage_adyn(0, 0);
        __syncthreads();
        for (int t = 0; t < nk; ++t) {
            const int cur = t & 1;
            if (t + 1 < nk) stage_adyn((t + 1) << 5, cur ^ 1);
            compute(cur);
            __syncthreads();
        }
    } else {
        // v6 loop: one vmcnt(0)+barrier per K-step; stage early, drain late
        stage(0, 0);
        vm_wait<0>();
        __builtin_amdgcn_s_barrier();
        for (int t = 0; t < nk; ++t) {
            const int cur = t & 1;
            if (t + 1 < nk) stage((t + 1) << 5, cur ^ 1);
            compute(cur);
            vm_wait<0>();                   // L2-resident loads: near-free
            __builtin_amdgcn_s_barrier();   // frees buf[cur], publishes t+1
        }
    }
    __syncthreads();   // panels free; epilogue reuses Sh

    if constexpr (MODE == MODE_QKV) {
        // epilogue: stage each 64x32 wave-tile in LDS, then emit b128
        // stores -- along hd for Q/K rows, TRANSPOSED along ss for V^T.
        bf16* Cw = Sh + w * 2048;       // per-wave 64 x 32 slice
        const int bb = (m0 + wr * 64) >> 11;   // wave-uniform batch index
#pragma unroll
        for (int j = 0; j < NJ32; ++j) {
            int nbase = n0 + wc * WN + j * 32;      // multiple of 32
            int which = nbase / D_;                 // wave-uniform
            int n2b   = nbase - which * D_;
            int h     = n2b / HD_;                  // wave-uniform (32 | 96)
            int hd0   = n2b - h * HD_;
            const void* bp = which == 0 ? b0 : (which == 1 ? b1 : b2);
            float bval = dynld(bp, n2b + l32, f32in);
            const int bh = bb * H_ + h;
#pragma unroll
            for (int i = 0; i < 2; ++i)
#pragma unroll
                for (int g = 0; g < 16; ++g) {
                    int rr = (g & 3) + 8 * (g >> 2) + 4 * kh;
                    float v = acc[i][j][g] + bval;
                    if (which == 0) v *= QSCALE;
                    Cw[(i * 32 + rr) * 32 + l32] = (bf16)v;
                }
            // same-wave LDS ops are in-order: reads below see all 64 lanes' writes
            if (which < 2) {
                // Q/K: out[(bh*S + ss)*HD + hd], b128 along hd
#pragma unroll
                for (int pass = 0; pass < 4; ++pass) {
                    int row = pass * 16 + (lane >> 2);
                    int c8  = (lane & 3) * 8;
                    bf16x8 cv = *(const bf16x8*)&Cw[row * 32 + c8];
                    int ss = (m0 + wr * 64 + row) & (S_ - 1);
                    size_t dst = (size_t)which * (MSZ * D_) + ((size_t)bh * S_ + ss) * HD_ + hd0 + c8;
                    *(bf16x8*)&out[dst] = cv;
                }
            } else {
                // V^T: out[2*MSZ*D + (bh*HD + hd)*S + ss], b128 along ss.
                int hd  = hd0 + l32;
                int ss0 = (m0 + wr * 64) & (S_ - 1);
                size_t rowb = (size_t)2 * (MSZ * D_) + ((size_t)bh * HD_ + hd) * S_ + ss0 + kh * 32;
#pragma unroll
                for (int oct = 0; oct < 4; ++oct) {
                    bf16x8 cv;
#pragma unroll
                    for (int e = 0; e < 8; ++e)
                        cv[e] = Cw[(kh * 32 + oct * 8 + e) * 32 + l32];
                    *(bf16x8*)&out[rowb + oct * 8] = cv;
                }
            }
        }
    } else {
        // dense epilogue: stage C through LDS, emit b128 loads/stores.
        bf16* Cw = Sh + w * 2048;        // per-wave 64 x 32 slice
        for (int j = 0; j < NJ32; ++j) {
            int nl = n0 + wc * WN + j * 32 + l32;
            float bval = boff >= 0 ? dynld(b0, boff + nl, f32in) : 0.f;
#pragma unroll
            for (int i = 0; i < 2; ++i)
#pragma unroll
                for (int g = 0; g < 16; ++g) {
                    int rr = (g & 3) + 8 * (g >> 2) + 4 * kh;
                    float v = acc[i][j][g] + bval;
                    if constexpr (MODE == MODE_GELU) v = gelu_f(v);
                    Cw[(i * 32 + rr) * 32 + l32] = (bf16)v;
                }
            // same-wave LDS ops are in-order: reads below see the writes above
#pragma unroll
            for (int pass = 0; pass < 4; ++pass) {
                int row = pass * 16 + (lane >> 2);
                int cc  = (lane & 3) * 8;
                bf16x8 cv = *(const bf16x8*)&Cw[row * 32 + cc];
                int m = m0 + wr * 64 + row;
                int n = n0 + wc * WN + j * 32 + cc;
                size_t off = (size_t)m * N + n;
                if constexpr (MODE == MODE_RES) {
                    bf16x8 o;
                    if (RESDYN && f32in) {
                        f32x4 r0 = *(const f32x4*)((const float*)res + off);
                        f32x4 r1 = *(const f32x4*)((const float*)res + off + 4);
#pragma unroll
                        for (int e = 0; e < 4; ++e) {
                            o[e]     = (bf16)((float)cv[e] + r0[e]);
                            o[e + 4] = (bf16)((float)cv[e + 4] + r1[e]);
                        }
                    } else {
                        bf16x8 rv = *(const bf16x8*)((const bf16*)res + off);
#pragma unroll
                        for (int e = 0; e < 8; ++e) o[e] = (bf16)((float)cv[e] + (float)rv[e]);
                    }
                    *(bf16x8*)&out[off] = o;
                } else {
                    *(bf16x8*)&out[off] = cv;
                }
            }
        }
    }
}

// Flash attention v2 + T5 setprio (R11: 88.9 -> 85.1us) + MFMA ROW-SUM
// (this round's single change): the softmax denominator l = P . 1 is a
// matmul with a ones B-operand, so two extra mfma(pf, ones) per qs per
// step accumulate lsacc on the 25%-busy MFMA pipe, replacing 24 VALU adds
// per wave-step on the 43%-busy VALU pipe PLUS the end-of-kernel
// cross-quad shfl_xor reduce + per-row __shfl fetch: the C layout
// (row=quad*4+r, cols all equal to the row-sum) puts each lane's output
// rows' sums exactly where the normalization needs them (lsacc[qs][r]).
// 256 threads (4 waves), Q-tile 128 (32 q-rows/wave as two 16-row
// subtiles), KV-tile 64.  Swapped QK^T (mfma(K,Q) -> S^T frag: lane holds
// q=l16, kv=quad*4+reg) so P packs as bf16x4 -> one ds_write_b64 per
// kv-16-tile; fixed-max offset -M0 folded into the MFMA accumulator init.
// K/V fragments shared across both q-subtiles; next-tile K/V prefetched
// into registers before compute (T14).  Q,K: [bh][S][96]; Vt_g: [bh][96][S].
// grid (B*H, S/128): x = bh -> XCD k owns bh === k (mod 8) -> K/V L2 locality.
__global__ __launch_bounds__(256, 2) void flash_kernel(
    const bf16* __restrict__ Q, const bf16* __restrict__ Kk,
    const bf16* __restrict__ Vt_g, bf16* __restrict__ ctx)
{
    __shared__ __align__(16) bf16 Ks[64][104];
    __shared__ __align__(16) bf16 Vs[96][72];
    __shared__ __align__(16) bf16 Ps[4][32][72];  // per-wave P [q][kv]

    const int tid  = threadIdx.x;
    const int w    = tid >> 6;
    const int lane = tid & 63;
    const int quad = lane >> 4;
    const int l16  = lane & 15;
    const int bh   = blockIdx.x;
    const size_t base = (size_t)bh * S_ * HD_;
    const int q0   = blockIdx.y * 128 + w * 32;

    // Q fragments (B-operand of swapped mfma): qf[qs][ch] = Q[q0+qs*16+l16][ch*32+quad*8..+7]
    bf16x8 qf[2][3];
#pragma unroll
    for (int qs = 0; qs < 2; ++qs)
#pragma unroll
        for (int ch = 0; ch < 3; ++ch)
            qf[qs][ch] = *(const bf16x8*)(Q + base + (size_t)(q0 + qs * 16 + l16) * HD_ + ch * 32 + quad * 8);

    f32x4 oacc[2][6];
#pragma unroll
    for (int qs = 0; qs < 2; ++qs)
#pragma unroll
        for (int c = 0; c < 6; ++c) oacc[qs][c] = (f32x4){0.f, 0.f, 0.f, 0.f};
    // row-sum accumulators (MFMA with ones B-operand); lsacc[qs][r] ends up
    // holding sum_kv P[q0+qs*16+quad*4+r][kv] in every lane of column l16.
    f32x4 lsacc[2];
    lsacc[0] = (f32x4){0.f, 0.f, 0.f, 0.f};
    lsacc[1] = (f32x4){0.f, 0.f, 0.f, 0.f};
    bf16x8 onesf;
#pragma unroll
    for (int e = 0; e < 8; ++e) onesf[e] = (bf16)1.0f;

    // staging maps: 256 threads x 3 chunks cover K (64x96) and V^T (96x64)
    int krow[3], kc8[3], vrow[3], vc8[3];
#pragma unroll
    for (int i = 0; i < 3; ++i) {
        int id = tid + i * 256;
        krow[i] = id / 12; kc8[i] = (id - krow[i] * 12) * 8;
        vrow[i] = id >> 3; vc8[i] = (id & 7) * 8;
    }

    bf16x8 kreg[3], vreg[3];
    // prologue: stage kv0 = 0
#pragma unroll
    for (int i = 0; i < 3; ++i) {
        kreg[i] = *(const bf16x8*)(Kk + base + (size_t)krow[i] * HD_ + kc8[i]);
        vreg[i] = *(const bf16x8*)(Vt_g + base + (size_t)vrow[i] * S_ + vc8[i]);
    }
#pragma unroll
    for (int i = 0; i < 3; ++i) {
        *(bf16x8*)(&Ks[krow[i]][kc8[i]]) = kreg[i];
        *(bf16x8*)(&Vs[vrow[i]][vc8[i]]) = vreg[i];
    }
    __syncthreads();

    for (int kv0 = 0; kv0 < S_; kv0 += 64) {
        const bool more = (kv0 + 64) < S_;
        if (more) {
            // issue next tile's loads now (T14): latency hides under compute
#pragma unroll
            for (int i = 0; i < 3; ++i) {
                kreg[i] = *(const bf16x8*)(Kk + base + (size_t)(kv0 + 64 + krow[i]) * HD_ + kc8[i]);
                vreg[i] = *(const bf16x8*)(Vt_g + base + (size_t)vrow[i] * S_ + kv0 + 64 + vc8[i]);
            }
        }

        // S^T = K (Q*QSCALE)^T, acc pre-loaded with -M0 (folds exponent offset)
        f32x4 sacc[2][4];
#pragma unroll
        for (int qs = 0; qs < 2; ++qs)
#pragma unroll
            for (int t = 0; t < 4; ++t)
                sacc[qs][t] = (f32x4){-M0_, -M0_, -M0_, -M0_};
        __builtin_amdgcn_s_setprio(1);
#pragma unroll
        for (int t = 0; t < 4; ++t)
#pragma unroll
            for (int ch = 0; ch < 3; ++ch) {
                bf16x8 kf = *(const bf16x8*)(&Ks[t * 16 + l16][ch * 32 + quad * 8]);
                sacc[0][t] = __builtin_amdgcn_mfma_f32_16x16x32_bf16(kf, qf[0][ch], sacc[0][t], 0, 0, 0);
                sacc[1][t] = __builtin_amdgcn_mfma_f32_16x16x32_bf16(kf, qf[1][ch], sacc[1][t], 0, 0, 0);
            }
        __builtin_amdgcn_s_setprio(0);

        // softmax: p = 2^sacc; lane holds q=l16, kv=t*16+quad*4+r -> packed b64 row writes
#pragma unroll
        for (int qs = 0; qs < 2; ++qs) {
            bf16* prow = &Ps[w][qs * 16 + l16][quad * 4];
#pragma unroll
            for (int t = 0; t < 4; ++t) {
                bf16x4 pv;
                pv[0] = (bf16)exp2f(sacc[qs][t][0]);
                pv[1] = (bf16)exp2f(sacc[qs][t][1]);
                pv[2] = (bf16)exp2f(sacc[qs][t][2]);
                pv[3] = (bf16)exp2f(sacc[qs][t][3]);
                *(bf16x4*)(prow + t * 16) = pv;
            }
        }
        // no barrier: Ps is per-wave (in-wave lgkmcnt ordering suffices)

        bf16x8 pf[2][2];
#pragma unroll
        for (int qs = 0; qs < 2; ++qs) {
            pf[qs][0] = *(const bf16x8*)(&Ps[w][qs * 16 + l16][quad * 8]);
            pf[qs][1] = *(const bf16x8*)(&Ps[w][qs * 16 + l16][32 + quad * 8]);
        }
        __builtin_amdgcn_s_setprio(1);
#pragma unroll
        for (int c = 0; c < 6; ++c) {
            bf16x8 vf0 = *(const bf16x8*)(&Vs[c * 16 + l16][quad * 8]);
            bf16x8 vf1 = *(const bf16x8*)(&Vs[c * 16 + l16][32 + quad * 8]);
            oacc[0][c] = __builtin_amdgcn_mfma_f32_16x16x32_bf16(pf[0][0], vf0, oacc[0][c], 0, 0, 0);
            oacc[0][c] = __builtin_amdgcn_mfma_f32_16x16x32_bf16(pf[0][1], vf1, oacc[0][c], 0, 0, 0);
            oacc[1][c] = __builtin_amdgcn_mfma_f32_16x16x32_bf16(pf[1][0], vf0, oacc[1][c], 0, 0, 0);
            oacc[1][c] = __builtin_amdgcn_mfma_f32_16x16x32_bf16(pf[1][1], vf1, oacc[1][c], 0, 0, 0);
        }
        // row-sums via the matrix pipe: l += P . 1
        lsacc[0] = __builtin_amdgcn_mfma_f32_16x16x32_bf16(pf[0][0], onesf, lsacc[0], 0, 0, 0);
        lsacc[0] = __builtin_amdgcn_mfma_f32_16x16x32_bf16(pf[0][1], onesf, lsacc[0], 0, 0, 0);
        lsacc[1] = __builtin_amdgcn_mfma_f32_16x16x32_bf16(pf[1][0], onesf, lsacc[1], 0, 0, 0);
        lsacc[1] = __builtin_amdgcn_mfma_f32_16x16x32_bf16(pf[1][1], onesf, lsacc[1], 0, 0, 0);
        __builtin_amdgcn_s_setprio(0);

        if (more) {
            __syncthreads();            // all waves done reading Ks/Vs
#pragma unroll
            for (int i = 0; i < 3; ++i) {
                *(bf16x8*)(&Ks[krow[i]][kc8[i]]) = kreg[i];
                *(bf16x8*)(&Vs[vrow[i]][vc8[i]]) = vreg[i];
            }
            __syncthreads();            // next tile visible
        }
    }

    // lsacc[qs][r] already holds this lane's output rows' sums (C layout:
    // row = quad*4+r, all columns equal) -- no cross-lane reduce needed.
    const int b = bh >> 3, h = bh & 7;
#pragma unroll
    for (int qs = 0; qs < 2; ++qs)
#pragma unroll
        for (int r = 0; r < 4; ++r) {
            float inv = 1.0f / lsacc[qs][r];
            int srow = q0 + qs * 16 + quad * 4 + r;
            size_t rowbase = ((size_t)b * S_ + srow) * D_ + h * HD_;
#pragma unroll
            for (int c = 0; c < 6; ++c)
                ctx[rowbase + c * 16 + l16] = (bf16)(oacc[qs][c][r] * inv);
        }
}

// LayerNorm over D=768: one wave per row (12 el/lane, bf16x4 vector I/O).
template<bool OUTDYN>
__global__ __launch_bounds__(256) void ln_kernel(
    const bf16* __restrict__ in, const void* __restrict__ g, const void* __restrict__ be,
    void* __restrict__ out, const void* __restrict__ sniffp)
{
    const bool f32in = sniff_f32(sniffp);
    const int w = threadIdx.x >> 6, lane = threadIdx.x & 63;
    const int row = blockIdx.x * 4 + w;
    const size_t rbase = (size_t)row * D_ + lane * 12;

    float v[12];
#pragma unroll
    for (int j = 0; j < 3; ++j) {
        bf16x4 t = *(const bf16x4*)(in + rbase + j * 4);
#pragma unroll
        for (int e = 0; e < 4; ++e) v[j * 4 + e] = (float)t[e];
    }
    float sum = 0.f;
#pragma unroll
    for (int j = 0; j < 12; ++j) sum += v[j];
#pragma unroll
    for (int off = 1; off < 64; off <<= 1) sum += __shfl_xor(sum, off);
    float mu = sum * (1.0f / D_);
    float sq = 0.f;
#pragma unroll
    for (int j = 0; j < 12; ++j) { v[j] -= mu; sq += v[j] * v[j]; }
#pragma unroll
    for (int off = 1; off < 64; off <<= 1) sq += __shfl_xor(sq, off);
    float rstd = rsqrtf(sq * (1.0f / D_) + 1e-5f);

    if (OUTDYN && f32in) {
        float* op = (float*)out + rbase;
#pragma unroll
        for (int j = 0; j < 3; ++j) {
            f32x4 t;
#pragma unroll
            for (int e = 0; e < 4; ++e) {
                int c = lane * 12 + j * 4 + e;
                t[e] = v[j * 4 + e] * rstd * dynld(g, c, true) + dynld(be, c, true);
            }
            *(f32x4*)(op + j * 4) = t;
        }
    } else {
        bf16* op = (bf16*)out + rbase;
#pragma unroll
        for (int j = 0; j < 3; ++j) {
            bf16x4 t;
#pragma unroll
            for (int e = 0; e < 4; ++e) {
                int c = lane * 12 + j * 4 + e;
                t[e] = (bf16)(v[j * 4 + e] * rstd * dynld(g, c, f32in) + dynld(be, c, f32in));
            }
            *(bf16x4*)(op + j * 4) = t;
        }
    }
}

// Wo/W1/W2 -> WoT|W1T|W2T, packed 1-D grid of 1296 tiles (no idle blocks)
__global__ __launch_bounds__(256) void transpose_mlp_kernel(
    const void* __restrict__ s0, const void* __restrict__ s1, const void* __restrict__ s2,
    bf16* __restrict__ dst)
{
    int id = blockIdx.x;
    const void* src;
    int R, C, r, c;
    size_t off;
    if (id < 144)      { src = s0; R = D_;    C = D_;    off = 0;
                         r = id / 12;          c = id % 12; }
    else if (id < 720) { src = s1; R = D_;    C = EXPD_; off = (size_t)D_ * D_;
                         int i = id - 144;     r = i / 48; c = i % 48; }
    else               { src = s2; R = EXPD_; C = D_;    off = (size_t)D_ * D_ + (size_t)D_ * EXPD_;
                         int i = id - 720;     r = i / 12; c = i % 12; }
    const bool f32in = sniff_f32(src);
    transpose_tile(src, dst + off, R, C, r * 64, c * 64, f32in);
}

extern "C" void kernel_launch(void* const* d_in, const int* in_sizes, int n_in,
                              void* d_out, int out_size, void* d_ws, size_t ws_size,
                              hipStream_t stream)
{
    (void)in_sizes; (void)n_in; (void)out_size;
    const void* x   = d_in[0];
    const void* Wq  = d_in[1];
    const void* bq  = d_in[2];
    const void* Wk  = d_in[3];
    const void* bk  = d_in[4];
    const void* Wv  = d_in[5];
    const void* bv  = d_in[6];
    const void* Wo  = d_in[7];
    const void* bo  = d_in[8];
    const void* g1  = d_in[9];
    const void* be1 = d_in[10];
    const void* W1  = d_in[11];
    const void* bf1 = d_in[12];
    const void* W2  = d_in[13];
    const void* bf2 = d_in[14];
    const void* g2  = d_in[15];
    const void* be2 = d_in[16];

    const size_t REG = (size_t)MSZ * D_ * 2;  // 12.58 MB
    char* p = (char*)d_ws;
    bf16* R0 = (bf16*)p;             // Q     -> x1
    bf16* R1 = (bf16*)(p + REG);     // K     -> WoT|W1T|W2T (10.0 MB)
    bf16* R2 = (bf16*)(p + 2 * REG); // V^T   -> (nsplit: hb) / (tier0: y2)
    bf16* R3 = (bf16*)(p + 3 * REG); // y1    -> (tier3: y2) / (nsplit: hb hi) / (tier0: hb)
    bf16* R4 = (bf16*)(p + 4 * REG); // xb (tier>=1); nsplit: -> y2

    // tiers: 3 = 9 REG (full h at p+4..8, xb at p+8) | 1 = 5 REG (nsplit) | 0 = 4 REG
    int tier = 0;
    if      (ws_size >= 9 * REG) tier = 3;
    else if (ws_size >= 5 * REG) tier = 1;
    bf16* xb = tier == 3 ? (bf16*)(p + 8 * REG) : R4;

    bf16* qkvT = (bf16*)d_out;       // WqT|WkT|WvT (3.54 MB) before flash
    bf16* ctx  = (bf16*)d_out;
    dim3 blk(256);
    const int MB8 = MSZ / 128 / 8;   // mstripe for full-M GEMMs = 8
    const int nCast = tier >= 1 ? MSZ * D_ / (256 * 8) : 0;

    // 0) merged prep: cast x -> xb (tier>=1) + transpose Wq/Wk/Wv -> qkvT
    prep_kernel<<<dim3(nCast + 432), blk, 0, stream>>>(
        x, xb, nCast, Wq, Wk, Wv, qkvT);

    // 1) fused QKV GEMM -> Q*QSCALE(R0), K(R1), V^T(R2).  grid 64x18 = 1152
    if (tier >= 1)
        gemm2_kernel<MODE_QKV, false, false, 128><<<dim3(64 * 18), blk, 0, stream>>>(
            xb, qkvT, bq, bk, bv, nullptr, R0, MSZ, 2304, D_, D_, D_, 0, MB8, Wq);
    else
        gemm2_kernel<MODE_QKV, true, false, 128><<<dim3(64 * 18), blk, 0, stream>>>(
            x, qkvT, bq, bk, bv, nullptr, R0, MSZ, 2304, D_, D_, D_, 0, MB8, Wq);

    // 2) flash attention -> ctx (d_out; qkvT dead). grid x = bh (XCD locality).
    flash_kernel<<<dim3(B_ * H_, S_ / 128), dim3(256), 0, stream>>>(R0, R1, R2, ctx);

    // 3) transpose Wo/W1/W2 into R1 (K dead)
    bf16* WoT = R1;
    bf16* W1T = WoT + (size_t)D_ * D_;
    bf16* W2T = W1T + (size_t)D_ * EXPD_;
    transpose_mlp_kernel<<<dim3(1296), blk, 0, stream>>>(Wo, W1, W2, WoT);

    // 4) y1 = ctx@Wo + bo + x -> R3   (BN=64, grid 64x12 = 768)
    if (tier >= 1)
        gemm2_kernel<MODE_RES, false, false, 64><<<dim3(64 * 12), blk, 0, stream>>>(
            ctx, WoT, bo, nullptr, nullptr, xb, R3, MSZ, D_, D_, D_, D_, 0, MB8, Wq);
    else
        gemm2_kernel<MODE_RES, false, true, 64><<<dim3(64 * 12), blk, 0, stream>>>(
            ctx, WoT, bo, nullptr, nullptr, x, R3, MSZ, D_, D_, D_, D_, 0, MB8, Wq);

    // 5) x1 = LN1(y1) -> R0 (Q dead)
    bf16* x1b = R0;
    ln_kernel<false><<<dim3(MSZ / 4), blk, 0, stream>>>(R3, g1, be1, x1b, Wq);

    // 6/7) FFN -> y2
    bf16* y2b;
    if (tier == 3) {
        // full h (4 REG at p+4..8); single W1 + single W2 (lda = EXPD_)
        bf16* hb = R4;
        y2b = R3;   // y1 dead
        gemm2_kernel<MODE_GELU, false, false, 128><<<dim3(64 * 24), blk, 0, stream>>>(
            x1b, W1T, bf1, nullptr, nullptr, nullptr, hb, MSZ, EXPD_, D_, D_, D_, 0, MB8, Wq);
        gemm2_kernel<MODE_RES, false, false, 64><<<dim3(64 * 12), blk, 0, stream>>>(
            hb, W2T, bf2, nullptr, nullptr, x1b, y2b, MSZ, D_, EXPD_, EXPD_, EXPD_, 0, MB8, Wq);
    } else if (tier == 1) {
        // N-split halves in hb = R2|R3 (V, y1 dead; hb contiguous stride 1536); y2 -> R4
        bf16* hb = R2;
        y2b = R4;
        gemm2_kernel<MODE_GELU, false, false, 128><<<dim3(64 * 12), blk, 0, stream>>>(
            x1b, W1T, bf1, nullptr, nullptr, nullptr, hb, MSZ, 1536, D_, D_, D_, 0, MB8, Wq);
        gemm2_kernel<MODE_RES, false, false, 64><<<dim3(64 * 12), blk, 0, stream>>>(
            hb, W2T, bf2, nullptr, nullptr, x1b, y2b, MSZ, D_, 1536, 1536, EXPD_, 0, MB8, Wq);
        gemm2_kernel<MODE_GELU, false, false, 128><<<dim3(64 * 12), blk, 0, stream>>>(
            x1b, W1T + (size_t)1536 * D_, bf1, nullptr, nullptr, nullptr, hb, MSZ, 1536, D_, D_, D_, 1536, MB8, Wq);
        gemm2_kernel<MODE_RES, false, false, 64><<<dim3(64 * 12), blk, 0, stream>>>(
            hb, W2T + 1536, nullptr, nullptr, nullptr, y2b, y2b, MSZ, D_, 1536, 1536, EXPD_, -1, MB8, Wq);
    } else {
        // 4-REG fallback: M-chunked FFN (hb = R3 after y1 consumed; y2 -> R2, V dead)
        bf16* hb = R3;
        y2b = R2;
        const int CH = 2048;   // 16 m-blocks -> mstripe 2
        for (int c0 = 0; c0 < MSZ; c0 += CH) {
            const bf16* x1c = x1b + (size_t)c0 * D_;
            gemm2_kernel<MODE_GELU, false, false, 128><<<dim3(16 * 24), blk, 0, stream>>>(
                x1c, W1T, bf1, nullptr, nullptr, nullptr, hb, CH, EXPD_, D_, D_, D_, 0, 2, Wq);
            gemm2_kernel<MODE_RES, false, false, 64><<<dim3(16 * 12), blk, 0, stream>>>(
                hb, W2T, bf2, nullptr, nullptr, x1c, y2b + (size_t)c0 * D_, CH, D_, EXPD_, EXPD_, EXPD_, 0, 2, Wq);
        }
    }

    // 8) out = LN2(y2) -> d_out
    ln_kernel<true><<<dim3(MSZ / 4), blk, 0, stream>>>(y2b, g2, be2, d_out, Wq);
}

// Round 14
// 410.073 us; speedup vs baseline: 1.0622x; 1.0622x over previous
//
#include <hip/hip_runtime.h>
#include <hip/hip_bf16.h>
#include <math.h>
#include <stdint.h>

// ---- problem constants ----
#define B_    4
#define S_    2048
#define D_    768
#define H_    8
#define HD_   96
#define EXPD_ 3072
#define MSZ   8192   // B*S

#define QSCALE 0.14724439f   // HD^-0.5 * log2(e), folded into Q at QKV epilogue
#define M0_    12.0f         // fixed softmax exponent offset

typedef __bf16 bf16;
typedef __bf16 bf16x4 __attribute__((ext_vector_type(4)));
typedef __bf16 bf16x8 __attribute__((ext_vector_type(8)));
typedef float  f32x4  __attribute__((ext_vector_type(4)));
typedef float  f32x16 __attribute__((ext_vector_type(16)));

typedef __attribute__((address_space(1))) const uint32_t gu32;
typedef __attribute__((address_space(3))) uint32_t lu32;

__device__ __forceinline__ void async_copy16(const void* g, void* l) {
    __builtin_amdgcn_global_load_lds((gu32*)g, (lu32*)l, 16, 0, 0);
}

template<int N> __device__ __forceinline__ void vm_wait() {
    if constexpr (N == 0)      asm volatile("s_waitcnt vmcnt(0)" ::: "memory");
    else if constexpr (N == 3) asm volatile("s_waitcnt vmcnt(3)" ::: "memory");
    else if constexpr (N == 4) asm volatile("s_waitcnt vmcnt(4)" ::: "memory");
    else static_assert(N == 0 || N == 3 || N == 4, "unsupported vmcnt");
}

// GELU (tanh form), computed via exp2: tanh(z) = (e^2z - 1)/(e^2z + 1)
// => gelu = x - x/(e^2z + 1).  Algebraically identical to the tanhf form
// but ~9 VALU ops vs the ~16-op OCML tanhf; saturates correctly at both
// tails (x - 0 = x for z >> 0; x - x = 0 for z << 0) with no inf*0.
__device__ __forceinline__ float gelu_f(float x) {
    float x3 = x * x * x;
    float z  = 0.7978845608028654f * (x + 0.044715f * x3);
    float t  = exp2f(2.8853900817779268f * z);   // e^{2z}
    return x - x / (t + 1.0f);
}

// Runtime dtype sniff: f32 buffer read as bf16 at even indices yields random
// exponents -> some |v|>=1e3 among 64 samples w.p. ~1. bf16 weights never trip.
__device__ __forceinline__ bool sniff_f32(const void* p) {
    const bf16* pb = (const bf16*)p;
    float v = (float)pb[2 * (threadIdx.x & 63)];
    bool big = !(fabsf(v) < 1000.0f);
    return __any(big) != 0;
}

__device__ __forceinline__ float dynld(const void* p, size_t i, bool f32in) {
    return f32in ? ((const float*)p)[i] : (float)((const bf16*)p)[i];
}

// Transpose 64x64 tile helper
__device__ __forceinline__ void transpose_tile(
    const void* __restrict__ src, bf16* __restrict__ dst, int R, int C,
    int r0, int c0, bool f32in)
{
    __shared__ bf16 t[64][65];
    const int tx = threadIdx.x & 63, ty = threadIdx.x >> 6;
#pragma unroll
    for (int i = 0; i < 16; ++i) {
        int rr = ty + i * 4;
        t[rr][tx] = (bf16)dynld(src, (size_t)(r0 + rr) * C + c0 + tx, f32in);
    }
    __syncthreads();
#pragma unroll
    for (int i = 0; i < 16; ++i) {
        int cc = ty + i * 4;
        dst[(size_t)(c0 + cc) * R + r0 + tx] = t[tx][cc];
    }
}

// Merged prep: cast x->bf16 (nCast blocks, 8 el/thread) + transpose
// Wq/Wk/Wv -> qkvT (432 blocks) + optionally (tier3) transpose Wo/W1/W2
// -> mlpT in R3 (1296 blocks; R3 is dead until the Wo GEMM, whose output
// re-homes to R2).  Removes the separate transpose_mlp dispatch from the
// critical path between flash and Wo.  Validated R12: prep-merging does
// not perturb the QKV GEMM (R8's regression was mlpT-in-d_out L2
// eviction -- mlpT stays in workspace here).
__global__ __launch_bounds__(256) void prep_kernel(
    const void* __restrict__ x, bf16* __restrict__ xb, int nCast,
    const void* __restrict__ Wq, const void* __restrict__ Wk, const void* __restrict__ Wv,
    bf16* __restrict__ qkvT,
    const void* __restrict__ Wo, const void* __restrict__ W1, const void* __restrict__ W2,
    bf16* __restrict__ mlpT)
{
    int id = blockIdx.x;
    if (id < nCast) {
        const bool f32in = sniff_f32(x);
        size_t i = ((size_t)id * 256 + threadIdx.x) * 8;
        if (f32in) {
            f32x4 a = *(const f32x4*)((const float*)x + i);
            f32x4 b = *(const f32x4*)((const float*)x + i + 4);
            bf16x8 r;
#pragma unroll
            for (int e = 0; e < 4; ++e) { r[e] = (bf16)a[e]; r[e + 4] = (bf16)b[e]; }
            *(bf16x8*)(xb + i) = r;
        } else {
            *(bf16x8*)(xb + i) = *(const bf16x8*)((const bf16*)x + i);
        }
        return;
    }
    id -= nCast;
    if (id < 432) {
        int z = id / 144, rem = id - z * 144;
        const void* src = z == 0 ? Wq : (z == 1 ? Wk : Wv);
        const bool f32in = sniff_f32(src);
        transpose_tile(src, qkvT + (size_t)z * D_ * D_, D_, D_,
                       (rem / 12) * 64, (rem % 12) * 64, f32in);
        return;
    }
    id -= 432;
    {
        const void* src; int R, C, r, c; size_t off;
        if (id < 144)      { src = Wo; R = D_;    C = D_;    off = 0;
                             r = id / 12;          c = id % 12; }
        else if (id < 720) { src = W1; R = D_;    C = EXPD_; off = (size_t)D_ * D_;
                             int i = id - 144;     r = i / 48; c = i % 48; }
        else               { src = W2; R = EXPD_; C = D_;    off = (size_t)D_ * D_ + (size_t)D_ * EXPD_;
                             int i = id - 720;     r = i / 12; c = i % 12; }
        const bool f32in = sniff_f32(src);
        transpose_tile(src, mlpT + off, R, C, r * 64, c * 64, f32in);
    }
}

#define MODE_QKV  0   // fused QKV: Q(*QSCALE),K -> [bh][S][HD]; V -> [bh][HD][S]
#define MODE_RES  1   // out bf16 = c + bias(if boff>=0) + res
#define MODE_GELU 2   // out bf16 = gelu(c + bias)

// 32x32x16-MFMA GEMM.  v6: 1-BARRIER-PER-STEP (T3-min template).
// BK=32 double-buffer, one vmcnt(0)+barrier per step (staging is
// L2-resident -> the drain is near-free), T2 XOR swizzle, setprio around
// the MFMA cluster.  16 KB/buffer (BN=128) -> 32 KB LDS -> 5 blocks/CU.
// Loop: stage(t+1) early; compute(t); vmcnt(0); s_barrier.
// Hazards: stage(t) drained by prev iter's vmcnt(0)+barrier before any
// wave's ds_read(t); stage(t+1) overwrites the buffer last read at
// compute(t-1), separated by the same barrier.
// C = A(MxK, row-stride lda) @ Bt(NxK, row-stride ldb)^T + bias[boff+n]
// (boff<0: none). Tile 128xBN, 4 waves. K must be a multiple of 64.
// XCD-aware 1-D grid decode (m fastest within per-XCD stripe).
template<int MODE, bool ADYN, bool RESDYN, int BN>
__global__ __launch_bounds__(256) void gemm2_kernel(
    const void* __restrict__ A, const bf16* __restrict__ Bt,
    const void* __restrict__ b0, const void* __restrict__ b1, const void* __restrict__ b2,
    const void* __restrict__ res, bf16* __restrict__ out,
    int M, int N, int K, int lda, int ldb, int boff, int mstripe,
    const void* __restrict__ sniffp)
{
    constexpr int WN   = BN / 2;
    constexpr int NJ32 = WN / 32;
    constexpr int ABUF = 4096;        // A panel: 128x32 el
    constexpr int BBUF = BN * 32;     // B panel: BNx32 el
    constexpr int BUF  = ABUF + BBUF;
    __shared__ __align__(16) bf16 Sh[2 * BUF];   // >= 8192 el for epilogue

    const bool f32in = sniff_f32(sniffp);
    const int tid  = threadIdx.x;
    const int w    = tid >> 6;
    const int lane = tid & 63;
    const int l32  = lane & 31;
    const int kh   = lane >> 5;     // k-half within a 16-wide mfma step
    const int wr   = w >> 1, wc = w & 1;

    // XCD-aware block decode (m-fast within stripe)
    const int lin  = blockIdx.x;
    const int xcd  = lin & 7;
    const int q    = lin >> 3;
    const int nb   = q / mstripe;
    const int mbin = q - nb * mstripe;
    const int m0   = (xcd * mstripe + mbin) * 128;
    const int n0   = nb * BN;

    const int rsub = lane >> 2;
    // swizzled global k-chunk for this lane's staging slot (T2, write side)
    const int cswz = (((lane & 3) ^ ((rsub >> 1) & 3))) * 8;
    // read-side XOR term (row bits 1..2; chunk bases are multiples of 8)
    const int xh   = (l32 >> 1) & 3;

    f32x16 acc[2][NJ32];
#pragma unroll
    for (int i = 0; i < 2; ++i)
#pragma unroll
        for (int j = 0; j < NJ32; ++j)
#pragma unroll
            for (int e = 0; e < 16; ++e) acc[i][j][e] = 0.f;

    const bf16*  Abf = (const bf16*)A;
    const float* Af  = (const float*)A;

    // stage K-tile at element offset k0 into buffer bsel (async bf16 path)
    auto stage = [&](int k0, int bsel) {
        bf16* As = Sh + bsel * BUF;
        bf16* Bs = As + ABUF;
#pragma unroll
        for (int p = 0; p < 2; ++p) {
            int row = p * 64 + w * 16;      // wave-uniform base row
            async_copy16(Abf + (size_t)(m0 + row + rsub) * lda + k0 + cswz,
                         &As[row * 32]);
        }
#pragma unroll
        for (int p = 0; p < BN / 64; ++p) {
            int row = p * 64 + w * 16;
            async_copy16(Bt + (size_t)(n0 + row + rsub) * ldb + k0 + cswz,
                         &Bs[row * 32]);
        }
    };

    // ds_read fragments (swizzled) + clustered MFMA for one K-tile
    auto compute = [&](int bsel) {
        const bf16* As = Sh + bsel * BUF;
        const bf16* Bs = As + ABUF;
        bf16x8 af[2][2], bfv[NJ32][2];
#pragma unroll
        for (int i = 0; i < 2; ++i)
#pragma unroll
            for (int ks = 0; ks < 2; ++ks)
                af[i][ks] = *(const bf16x8*)(&As[(wr * 64 + i * 32 + l32) * 32
                                                + (((ks * 2 + kh) ^ xh) * 8)]);
#pragma unroll
        for (int j = 0; j < NJ32; ++j)
#pragma unroll
            for (int ks = 0; ks < 2; ++ks)
                bfv[j][ks] = *(const bf16x8*)(&Bs[(wc * WN + j * 32 + l32) * 32
                                                  + (((ks * 2 + kh) ^ xh) * 8)]);
        asm volatile("s_waitcnt lgkmcnt(0)" ::: "memory");
        __builtin_amdgcn_sched_barrier(0);
        __builtin_amdgcn_s_setprio(1);
#pragma unroll
        for (int i = 0; i < 2; ++i)
#pragma unroll
            for (int j = 0; j < NJ32; ++j)
#pragma unroll
                for (int ks = 0; ks < 2; ++ks)
                    acc[i][j] = __builtin_amdgcn_mfma_f32_32x32x16_bf16(af[i][ks], bfv[j][ks], acc[i][j], 0, 0, 0);
        __builtin_amdgcn_s_setprio(0);
    };

    const int nk = K >> 5;
    if constexpr (ADYN) {
        // legacy drain loop (f32-A fallback; LDS writes need full drains)
        auto stage_adyn = [&](int k0, int bsel) {
            bf16* As = Sh + bsel * BUF;
            bf16* Bs = As + ABUF;
            if (f32in) {
#pragma unroll
                for (int p = 0; p < 2; ++p) {
                    int row = p * 64 + w * 16 + rsub;
                    const float* sp = Af + (size_t)(m0 + row) * lda + k0 + cswz;
                    f32x4 u0 = *(const f32x4*)sp;
                    f32x4 u1 = *(const f32x4*)(sp + 4);
                    bf16x8 v;
#pragma unroll
                    for (int e = 0; e < 4; ++e) { v[e] = (bf16)u0[e]; v[e + 4] = (bf16)u1[e]; }
                    *(bf16x8*)(&As[row * 32 + (lane & 3) * 8]) = v;
                }
            } else {
#pragma unroll
                for (int p = 0; p < 2; ++p) {
                    int row = p * 64 + w * 16;
                    async_copy16(Abf + (size_t)(m0 + row + rsub) * lda + k0 + cswz,
                                 &As[row * 32]);
                }
            }
#pragma unroll
            for (int p = 0; p < BN / 64; ++p) {
                int row = p * 64 + w * 16;
                async_copy16(Bt + (size_t)(n0 + row + rsub) * ldb + k0 + cswz,
                             &Bs[row * 32]);
            }
        };
        stage_adyn(0, 0);
        __syncthreads();
        for (int t = 0; t < nk; ++t) {
            const int cur = t & 1;
            if (t + 1 < nk) stage_adyn((t + 1) << 5, cur ^ 1);
            compute(cur);
            __syncthreads();
        }
    } else {
        // v6 loop: one vmcnt(0)+barrier per K-step; stage early, drain late
        stage(0, 0);
        vm_wait<0>();
        __builtin_amdgcn_s_barrier();
        for (int t = 0; t < nk; ++t) {
            const int cur = t & 1;
            if (t + 1 < nk) stage((t + 1) << 5, cur ^ 1);
            compute(cur);
            vm_wait<0>();                   // L2-resident loads: near-free
            __builtin_amdgcn_s_barrier();   // frees buf[cur], publishes t+1
        }
    }
    __syncthreads();   // panels free; epilogue reuses Sh

    if constexpr (MODE == MODE_QKV) {
        // epilogue: stage each 64x32 wave-tile in LDS, then emit b128
        // stores -- along hd for Q/K rows, TRANSPOSED along ss for V^T.
        bf16* Cw = Sh + w * 2048;       // per-wave 64 x 32 slice
        const int bb = (m0 + wr * 64) >> 11;   // wave-uniform batch index
#pragma unroll
        for (int j = 0; j < NJ32; ++j) {
            int nbase = n0 + wc * WN + j * 32;      // multiple of 32
            int which = nbase / D_;                 // wave-uniform
            int n2b   = nbase - which * D_;
            int h     = n2b / HD_;                  // wave-uniform (32 | 96)
            int hd0   = n2b - h * HD_;
            const void* bp = which == 0 ? b0 : (which == 1 ? b1 : b2);
            float bval = dynld(bp, n2b + l32, f32in);
            const int bh = bb * H_ + h;
#pragma unroll
            for (int i = 0; i < 2; ++i)
#pragma unroll
                for (int g = 0; g < 16; ++g) {
                    int rr = (g & 3) + 8 * (g >> 2) + 4 * kh;
                    float v = acc[i][j][g] + bval;
                    if (which == 0) v *= QSCALE;
                    Cw[(i * 32 + rr) * 32 + l32] = (bf16)v;
                }
            // same-wave LDS ops are in-order: reads below see all 64 lanes' writes
            if (which < 2) {
                // Q/K: out[(bh*S + ss)*HD + hd], b128 along hd
#pragma unroll
                for (int pass = 0; pass < 4; ++pass) {
                    int row = pass * 16 + (lane >> 2);
                    int c8  = (lane & 3) * 8;
                    bf16x8 cv = *(const bf16x8*)&Cw[row * 32 + c8];
                    int ss = (m0 + wr * 64 + row) & (S_ - 1);
                    size_t dst = (size_t)which * (MSZ * D_) + ((size_t)bh * S_ + ss) * HD_ + hd0 + c8;
                    *(bf16x8*)&out[dst] = cv;
                }
            } else {
                // V^T: out[2*MSZ*D + (bh*HD + hd)*S + ss], b128 along ss.
                int hd  = hd0 + l32;
                int ss0 = (m0 + wr * 64) & (S_ - 1);
                size_t rowb = (size_t)2 * (MSZ * D_) + ((size_t)bh * HD_ + hd) * S_ + ss0 + kh * 32;
#pragma unroll
                for (int oct = 0; oct < 4; ++oct) {
                    bf16x8 cv;
#pragma unroll
                    for (int e = 0; e < 8; ++e)
                        cv[e] = Cw[(kh * 32 + oct * 8 + e) * 32 + l32];
                    *(bf16x8*)&out[rowb + oct * 8] = cv;
                }
            }
        }
    } else {
        // dense epilogue: stage C through LDS, emit b128 loads/stores.
        bf16* Cw = Sh + w * 2048;        // per-wave 64 x 32 slice
        for (int j = 0; j < NJ32; ++j) {
            int nl = n0 + wc * WN + j * 32 + l32;
            float bval = boff >= 0 ? dynld(b0, boff + nl, f32in) : 0.f;
#pragma unroll
            for (int i = 0; i < 2; ++i)
#pragma unroll
                for (int g = 0; g < 16; ++g) {
                    int rr = (g & 3) + 8 * (g >> 2) + 4 * kh;
                    float v = acc[i][j][g] + bval;
                    if constexpr (MODE == MODE_GELU) v = gelu_f(v);
                    Cw[(i * 32 + rr) * 32 + l32] = (bf16)v;
                }
            // same-wave LDS ops are in-order: reads below see the writes above
#pragma unroll
            for (int pass = 0; pass < 4; ++pass) {
                int row = pass * 16 + (lane >> 2);
                int cc  = (lane & 3) * 8;
                bf16x8 cv = *(const bf16x8*)&Cw[row * 32 + cc];
                int m = m0 + wr * 64 + row;
                int n = n0 + wc * WN + j * 32 + cc;
                size_t off = (size_t)m * N + n;
                if constexpr (MODE == MODE_RES) {
                    bf16x8 o;
                    if (RESDYN && f32in) {
                        f32x4 r0 = *(const f32x4*)((const float*)res + off);
                        f32x4 r1 = *(const f32x4*)((const float*)res + off + 4);
#pragma unroll
                        for (int e = 0; e < 4; ++e) {
                            o[e]     = (bf16)((float)cv[e] + r0[e]);
                            o[e + 4] = (bf16)((float)cv[e + 4] + r1[e]);
                        }
                    } else {
                        bf16x8 rv = *(const bf16x8*)((const bf16*)res + off);
#pragma unroll
                        for (int e = 0; e < 8; ++e) o[e] = (bf16)((float)cv[e] + (float)rv[e]);
                    }
                    *(bf16x8*)&out[off] = o;
                } else {
                    *(bf16x8*)&out[off] = cv;
                }
            }
        }
    }
}

// Flash attention v2 + T5 setprio (R11: 88.9 -> 85.1us) + MFMA row-sum
// (R13: 83.5 -> 78.8us, MfmaUtil 25 -> 29.5): softmax denominator l = P.1
// computed as mfma(pf, ones) on the matrix pipe, replacing per-step VALU
// adds + end-of-kernel shuffles; lsacc[qs][r] holds each lane's output
// rows' sums directly (C layout: row=quad*4+r, all cols equal).
// 256 threads (4 waves), Q-tile 128 (32 q-rows/wave as two 16-row
// subtiles), KV-tile 64.  Swapped QK^T (mfma(K,Q) -> S^T frag: lane holds
// q=l16, kv=quad*4+reg) so P packs as bf16x4 -> one ds_write_b64 per
// kv-16-tile; fixed-max offset -M0 folded into the MFMA accumulator init.
// K/V fragments shared across both q-subtiles; next-tile K/V prefetched
// into registers before compute (T14).  Q,K: [bh][S][96]; Vt_g: [bh][96][S].
// grid (B*H, S/128): x = bh -> XCD k owns bh === k (mod 8) -> K/V L2 locality.
__global__ __launch_bounds__(256, 2) void flash_kernel(
    const bf16* __restrict__ Q, const bf16* __restrict__ Kk,
    const bf16* __restrict__ Vt_g, bf16* __restrict__ ctx)
{
    __shared__ __align__(16) bf16 Ks[64][104];
    __shared__ __align__(16) bf16 Vs[96][72];
    __shared__ __align__(16) bf16 Ps[4][32][72];  // per-wave P [q][kv]

    const int tid  = threadIdx.x;
    const int w    = tid >> 6;
    const int lane = tid & 63;
    const int quad = lane >> 4;
    const int l16  = lane & 15;
    const int bh   = blockIdx.x;
    const size_t base = (size_t)bh * S_ * HD_;
    const int q0   = blockIdx.y * 128 + w * 32;

    // Q fragments (B-operand of swapped mfma): qf[qs][ch] = Q[q0+qs*16+l16][ch*32+quad*8..+7]
    bf16x8 qf[2][3];
#pragma unroll
    for (int qs = 0; qs < 2; ++qs)
#pragma unroll
        for (int ch = 0; ch < 3; ++ch)
            qf[qs][ch] = *(const bf16x8*)(Q + base + (size_t)(q0 + qs * 16 + l16) * HD_ + ch * 32 + quad * 8);

    f32x4 oacc[2][6];
#pragma unroll
    for (int qs = 0; qs < 2; ++qs)
#pragma unroll
        for (int c = 0; c < 6; ++c) oacc[qs][c] = (f32x4){0.f, 0.f, 0.f, 0.f};
    // row-sum accumulators (MFMA with ones B-operand); lsacc[qs][r] ends up
    // holding sum_kv P[q0+qs*16+quad*4+r][kv] in every lane of column l16.
    f32x4 lsacc[2];
    lsacc[0] = (f32x4){0.f, 0.f, 0.f, 0.f};
    lsacc[1] = (f32x4){0.f, 0.f, 0.f, 0.f};
    bf16x8 onesf;
#pragma unroll
    for (int e = 0; e < 8; ++e) onesf[e] = (bf16)1.0f;

    // staging maps: 256 threads x 3 chunks cover K (64x96) and V^T (96x64)
    int krow[3], kc8[3], vrow[3], vc8[3];
#pragma unroll
    for (int i = 0; i < 3; ++i) {
        int id = tid + i * 256;
        krow[i] = id / 12; kc8[i] = (id - krow[i] * 12) * 8;
        vrow[i] = id >> 3; vc8[i] = (id & 7) * 8;
    }

    bf16x8 kreg[3], vreg[3];
    // prologue: stage kv0 = 0
#pragma unroll
    for (int i = 0; i < 3; ++i) {
        kreg[i] = *(const bf16x8*)(Kk + base + (size_t)krow[i] * HD_ + kc8[i]);
        vreg[i] = *(const bf16x8*)(Vt_g + base + (size_t)vrow[i] * S_ + vc8[i]);
    }
#pragma unroll
    for (int i = 0; i < 3; ++i) {
        *(bf16x8*)(&Ks[krow[i]][kc8[i]]) = kreg[i];
        *(bf16x8*)(&Vs[vrow[i]][vc8[i]]) = vreg[i];
    }
    __syncthreads();

    for (int kv0 = 0; kv0 < S_; kv0 += 64) {
        const bool more = (kv0 + 64) < S_;
        if (more) {
            // issue next tile's loads now (T14): latency hides under compute
#pragma unroll
            for (int i = 0; i < 3; ++i) {
                kreg[i] = *(const bf16x8*)(Kk + base + (size_t)(kv0 + 64 + krow[i]) * HD_ + kc8[i]);
                vreg[i] = *(const bf16x8*)(Vt_g + base + (size_t)vrow[i] * S_ + kv0 + 64 + vc8[i]);
            }
        }

        // S^T = K (Q*QSCALE)^T, acc pre-loaded with -M0 (folds exponent offset)
        f32x4 sacc[2][4];
#pragma unroll
        for (int qs = 0; qs < 2; ++qs)
#pragma unroll
            for (int t = 0; t < 4; ++t)
                sacc[qs][t] = (f32x4){-M0_, -M0_, -M0_, -M0_};
        __builtin_amdgcn_s_setprio(1);
#pragma unroll
        for (int t = 0; t < 4; ++t)
#pragma unroll
            for (int ch = 0; ch < 3; ++ch) {
                bf16x8 kf = *(const bf16x8*)(&Ks[t * 16 + l16][ch * 32 + quad * 8]);
                sacc[0][t] = __builtin_amdgcn_mfma_f32_16x16x32_bf16(kf, qf[0][ch], sacc[0][t], 0, 0, 0);
                sacc[1][t] = __builtin_amdgcn_mfma_f32_16x16x32_bf16(kf, qf[1][ch], sacc[1][t], 0, 0, 0);
            }
        __builtin_amdgcn_s_setprio(0);

        // softmax: p = 2^sacc; lane holds q=l16, kv=t*16+quad*4+r -> packed b64 row writes
#pragma unroll
        for (int qs = 0; qs < 2; ++qs) {
            bf16* prow = &Ps[w][qs * 16 + l16][quad * 4];
#pragma unroll
            for (int t = 0; t < 4; ++t) {
                bf16x4 pv;
                pv[0] = (bf16)exp2f(sacc[qs][t][0]);
                pv[1] = (bf16)exp2f(sacc[qs][t][1]);
                pv[2] = (bf16)exp2f(sacc[qs][t][2]);
                pv[3] = (bf16)exp2f(sacc[qs][t][3]);
                *(bf16x4*)(prow + t * 16) = pv;
            }
        }
        // no barrier: Ps is per-wave (in-wave lgkmcnt ordering suffices)

        bf16x8 pf[2][2];
#pragma unroll
        for (int qs = 0; qs < 2; ++qs) {
            pf[qs][0] = *(const bf16x8*)(&Ps[w][qs * 16 + l16][quad * 8]);
            pf[qs][1] = *(const bf16x8*)(&Ps[w][qs * 16 + l16][32 + quad * 8]);
        }
        __builtin_amdgcn_s_setprio(1);
#pragma unroll
        for (int c = 0; c < 6; ++c) {
            bf16x8 vf0 = *(const bf16x8*)(&Vs[c * 16 + l16][quad * 8]);
            bf16x8 vf1 = *(const bf16x8*)(&Vs[c * 16 + l16][32 + quad * 8]);
            oacc[0][c] = __builtin_amdgcn_mfma_f32_16x16x32_bf16(pf[0][0], vf0, oacc[0][c], 0, 0, 0);
            oacc[0][c] = __builtin_amdgcn_mfma_f32_16x16x32_bf16(pf[0][1], vf1, oacc[0][c], 0, 0, 0);
            oacc[1][c] = __builtin_amdgcn_mfma_f32_16x16x32_bf16(pf[1][0], vf0, oacc[1][c], 0, 0, 0);
            oacc[1][c] = __builtin_amdgcn_mfma_f32_16x16x32_bf16(pf[1][1], vf1, oacc[1][c], 0, 0, 0);
        }
        // row-sums via the matrix pipe: l += P . 1
        lsacc[0] = __builtin_amdgcn_mfma_f32_16x16x32_bf16(pf[0][0], onesf, lsacc[0], 0, 0, 0);
        lsacc[0] = __builtin_amdgcn_mfma_f32_16x16x32_bf16(pf[0][1], onesf, lsacc[0], 0, 0, 0);
        lsacc[1] = __builtin_amdgcn_mfma_f32_16x16x32_bf16(pf[1][0], onesf, lsacc[1], 0, 0, 0);
        lsacc[1] = __builtin_amdgcn_mfma_f32_16x16x32_bf16(pf[1][1], onesf, lsacc[1], 0, 0, 0);
        __builtin_amdgcn_s_setprio(0);

        if (more) {
            __syncthreads();            // all waves done reading Ks/Vs
#pragma unroll
            for (int i = 0; i < 3; ++i) {
                *(bf16x8*)(&Ks[krow[i]][kc8[i]]) = kreg[i];
                *(bf16x8*)(&Vs[vrow[i]][vc8[i]]) = vreg[i];
            }
            __syncthreads();            // next tile visible
        }
    }

    // lsacc[qs][r] already holds this lane's output rows' sums (C layout:
    // row = quad*4+r, all columns equal) -- no cross-lane reduce needed.
    const int b = bh >> 3, h = bh & 7;
#pragma unroll
    for (int qs = 0; qs < 2; ++qs)
#pragma unroll
        for (int r = 0; r < 4; ++r) {
            float inv = 1.0f / lsacc[qs][r];
            int srow = q0 + qs * 16 + quad * 4 + r;
            size_t rowbase = ((size_t)b * S_ + srow) * D_ + h * HD_;
#pragma unroll
            for (int c = 0; c < 6; ++c)
                ctx[rowbase + c * 16 + l16] = (bf16)(oacc[qs][c][r] * inv);
        }
}

// LayerNorm over D=768: one wave per row (12 el/lane, bf16x4 vector I/O).
template<bool OUTDYN>
__global__ __launch_bounds__(256) void ln_kernel(
    const bf16* __restrict__ in, const void* __restrict__ g, const void* __restrict__ be,
    void* __restrict__ out, const void* __restrict__ sniffp)
{
    const bool f32in = sniff_f32(sniffp);
    const int w = threadIdx.x >> 6, lane = threadIdx.x & 63;
    const int row = blockIdx.x * 4 + w;
    const size_t rbase = (size_t)row * D_ + lane * 12;

    float v[12];
#pragma unroll
    for (int j = 0; j < 3; ++j) {
        bf16x4 t = *(const bf16x4*)(in + rbase + j * 4);
#pragma unroll
        for (int e = 0; e < 4; ++e) v[j * 4 + e] = (float)t[e];
    }
    float sum = 0.f;
#pragma unroll
    for (int j = 0; j < 12; ++j) sum += v[j];
#pragma unroll
    for (int off = 1; off < 64; off <<= 1) sum += __shfl_xor(sum, off);
    float mu = sum * (1.0f / D_);
    float sq = 0.f;
#pragma unroll
    for (int j = 0; j < 12; ++j) { v[j] -= mu; sq += v[j] * v[j]; }
#pragma unroll
    for (int off = 1; off < 64; off <<= 1) sq += __shfl_xor(sq, off);
    float rstd = rsqrtf(sq * (1.0f / D_) + 1e-5f);

    if (OUTDYN && f32in) {
        float* op = (float*)out + rbase;
#pragma unroll
        for (int j = 0; j < 3; ++j) {
            f32x4 t;
#pragma unroll
            for (int e = 0; e < 4; ++e) {
                int c = lane * 12 + j * 4 + e;
                t[e] = v[j * 4 + e] * rstd * dynld(g, c, true) + dynld(be, c, true);
            }
            *(f32x4*)(op + j * 4) = t;
        }
    } else {
        bf16* op = (bf16*)out + rbase;
#pragma unroll
        for (int j = 0; j < 3; ++j) {
            bf16x4 t;
#pragma unroll
            for (int e = 0; e < 4; ++e) {
                int c = lane * 12 + j * 4 + e;
                t[e] = (bf16)(v[j * 4 + e] * rstd * dynld(g, c, f32in) + dynld(be, c, f32in));
            }
            *(bf16x4*)(op + j * 4) = t;
        }
    }
}

// Wo/W1/W2 -> WoT|W1T|W2T (fallback for tier<3; tier3 uses prep_kernel)
__global__ __launch_bounds__(256) void transpose_mlp_kernel(
    const void* __restrict__ s0, const void* __restrict__ s1, const void* __restrict__ s2,
    bf16* __restrict__ dst)
{
    int id = blockIdx.x;
    const void* src;
    int R, C, r, c;
    size_t off;
    if (id < 144)      { src = s0; R = D_;    C = D_;    off = 0;
                         r = id / 12;          c = id % 12; }
    else if (id < 720) { src = s1; R = D_;    C = EXPD_; off = (size_t)D_ * D_;
                         int i = id - 144;     r = i / 48; c = i % 48; }
    else               { src = s2; R = EXPD_; C = D_;    off = (size_t)D_ * D_ + (size_t)D_ * EXPD_;
                         int i = id - 720;     r = i / 12; c = i % 12; }
    const bool f32in = sniff_f32(src);
    transpose_tile(src, dst + off, R, C, r * 64, c * 64, f32in);
}

extern "C" void kernel_launch(void* const* d_in, const int* in_sizes, int n_in,
                              void* d_out, int out_size, void* d_ws, size_t ws_size,
                              hipStream_t stream)
{
    (void)in_sizes; (void)n_in; (void)out_size;
    const void* x   = d_in[0];
    const void* Wq  = d_in[1];
    const void* bq  = d_in[2];
    const void* Wk  = d_in[3];
    const void* bk  = d_in[4];
    const void* Wv  = d_in[5];
    const void* bv  = d_in[6];
    const void* Wo  = d_in[7];
    const void* bo  = d_in[8];
    const void* g1  = d_in[9];
    const void* be1 = d_in[10];
    const void* W1  = d_in[11];
    const void* bf1 = d_in[12];
    const void* W2  = d_in[13];
    const void* bf2 = d_in[14];
    const void* g2  = d_in[15];
    const void* be2 = d_in[16];

    const size_t REG = (size_t)MSZ * D_ * 2;  // 12.58 MB
    char* p = (char*)d_ws;
    bf16* R0 = (bf16*)p;             // Q     -> x1
    bf16* R1 = (bf16*)(p + REG);     // K     (tier<3: -> WoT|W1T|W2T)
    bf16* R2 = (bf16*)(p + 2 * REG); // V^T   (tier3: -> y1) / nsplit: hb / tier0: y2
    bf16* R3 = (bf16*)(p + 3 * REG); // tier3: mlpT (from prep) | tier<3: y1 -> ...
    bf16* R4 = (bf16*)(p + 4 * REG); // hb (tier3, 4 REG); xb (tier1); nsplit: -> y2

    // tiers: 3 = 9 REG (h at p+4..8, xb at p+8) | 1 = 5 REG (nsplit) | 0 = 4 REG
    int tier = 0;
    if      (ws_size >= 9 * REG) tier = 3;
    else if (ws_size >= 5 * REG) tier = 1;
    bf16* xb = tier == 3 ? (bf16*)(p + 8 * REG) : R4;

    bf16* qkvT = (bf16*)d_out;       // WqT|WkT|WvT (3.54 MB) before flash
    bf16* ctx  = (bf16*)d_out;
    dim3 blk(256);
    const int MB8 = MSZ / 128 / 8;   // mstripe for full-M GEMMs = 8
    const int nCast = tier >= 1 ? MSZ * D_ / (256 * 8) : 0;

    // 0) merged prep: cast x -> xb + transpose Wq/Wk/Wv -> qkvT
    //    (+ tier3: transpose Wo/W1/W2 -> mlpT in R3, dead until Wo GEMM)
    bf16* mlpT = tier == 3 ? R3 : R1;
    prep_kernel<<<dim3(nCast + 432 + (tier == 3 ? 1296 : 0)), blk, 0, stream>>>(
        x, xb, nCast, Wq, Wk, Wv, qkvT, Wo, W1, W2, mlpT);

    // 1) fused QKV GEMM -> Q*QSCALE(R0), K(R1), V^T(R2).  grid 64x18 = 1152
    if (tier >= 1)
        gemm2_kernel<MODE_QKV, false, false, 128><<<dim3(64 * 18), blk, 0, stream>>>(
            xb, qkvT, bq, bk, bv, nullptr, R0, MSZ, 2304, D_, D_, D_, 0, MB8, Wq);
    else
        gemm2_kernel<MODE_QKV, true, false, 128><<<dim3(64 * 18), blk, 0, stream>>>(
            x, qkvT, bq, bk, bv, nullptr, R0, MSZ, 2304, D_, D_, D_, 0, MB8, Wq);

    // 2) flash attention -> ctx (d_out; qkvT dead). grid x = bh (XCD locality).
    flash_kernel<<<dim3(B_ * H_, S_ / 128), dim3(256), 0, stream>>>(R0, R1, R2, ctx);

    // 2b) tier<3: transpose Wo/W1/W2 into R1 (K dead)
    if (tier != 3)
        transpose_mlp_kernel<<<dim3(1296), blk, 0, stream>>>(Wo, W1, W2, mlpT);

    bf16* WoT = mlpT;
    bf16* W1T = WoT + (size_t)D_ * D_;
    bf16* W2T = W1T + (size_t)D_ * EXPD_;

    // 3) y1 = ctx@Wo + bo + x.  tier3: -> R2 (V^T dead); tier<3: -> R3
    bf16* y1b = tier == 3 ? R2 : R3;
    if (tier >= 1)
        gemm2_kernel<MODE_RES, false, false, 64><<<dim3(64 * 12), blk, 0, stream>>>(
            ctx, WoT, bo, nullptr, nullptr, xb, y1b, MSZ, D_, D_, D_, D_, 0, MB8, Wq);
    else
        gemm2_kernel<MODE_RES, false, true, 64><<<dim3(64 * 12), blk, 0, stream>>>(
            ctx, WoT, bo, nullptr, nullptr, x, y1b, MSZ, D_, D_, D_, D_, 0, MB8, Wq);

    // 4) x1 = LN1(y1) -> R0 (Q dead)
    bf16* x1b = R0;
    ln_kernel<false><<<dim3(MSZ / 4), blk, 0, stream>>>(y1b, g1, be1, x1b, Wq);

    // 5/6) FFN -> y2
    bf16* y2b;
    if (tier == 3) {
        // full h (4 REG at p+4..8); y2 -> xb slot (R8; xb dead after y1)
        bf16* hb = R4;
        y2b = xb;
        gemm2_kernel<MODE_GELU, false, false, 128><<<dim3(64 * 24), blk, 0, stream>>>(
            x1b, W1T, bf1, nullptr, nullptr, nullptr, hb, MSZ, EXPD_, D_, D_, D_, 0, MB8, Wq);
        gemm2_kernel<MODE_RES, false, false, 64><<<dim3(64 * 12), blk, 0, stream>>>(
            hb, W2T, bf2, nullptr, nullptr, x1b, y2b, MSZ, D_, EXPD_, EXPD_, EXPD_, 0, MB8, Wq);
    } else if (tier == 1) {
        // N-split halves in hb = R2|R3 (V, y1 dead; hb contiguous stride 1536); y2 -> R4
        bf16* hb = R2;
        y2b = R4;
        gemm2_kernel<MODE_GELU, false, false, 128><<<dim3(64 * 12), blk, 0, stream>>>(
            x1b, W1T, bf1, nullptr, nullptr, nullptr, hb, MSZ, 1536, D_, D_, D_, 0, MB8, Wq);
        gemm2_kernel<MODE_RES, false, false, 64><<<dim3(64 * 12), blk, 0, stream>>>(
            hb, W2T, bf2, nullptr, nullptr, x1b, y2b, MSZ, D_, 1536, 1536, EXPD_, 0, MB8, Wq);
        gemm2_kernel<MODE_GELU, false, false, 128><<<dim3(64 * 12), blk, 0, stream>>>(
            x1b, W1T + (size_t)1536 * D_, bf1, nullptr, nullptr, nullptr, hb, MSZ, 1536, D_, D_, D_, 1536, MB8, Wq);
        gemm2_kernel<MODE_RES, false, false, 64><<<dim3(64 * 12), blk, 0, stream>>>(
            hb, W2T + 1536, nullptr, nullptr, nullptr, y2b, y2b, MSZ, D_, 1536, 1536, EXPD_, -1, MB8, Wq);
    } else {
        // 4-REG fallback: M-chunked FFN (hb = R3 after y1 consumed; y2 -> R2, V dead)
        bf16* hb = R3;
        y2b = R2;
        const int CH = 2048;   // 16 m-blocks -> mstripe 2
        for (int c0 = 0; c0 < MSZ; c0 += CH) {
            const bf16* x1c = x1b + (size_t)c0 * D_;
            gemm2_kernel<MODE_GELU, false, false, 128><<<dim3(16 * 24), blk, 0, stream>>>(
                x1c, W1T, bf1, nullptr, nullptr, nullptr, hb, CH, EXPD_, D_, D_, D_, 0, 2, Wq);
            gemm2_kernel<MODE_RES, false, false, 64><<<dim3(16 * 12), blk, 0, stream>>>(
                hb, W2T, bf2, nullptr, nullptr, x1c, y2b + (size_t)c0 * D_, CH, D_, EXPD_, EXPD_, EXPD_, 0, 2, Wq);
        }
    }

    // 7) out = LN2(y2) -> d_out
    ln_kernel<true><<<dim3(MSZ / 4), blk, 0, stream>>>(y2b, g2, be2, d_out, Wq);
}

// Round 15
// 406.056 us; speedup vs baseline: 1.0727x; 1.0099x over previous
//
#include <hip/hip_runtime.h>
#include <hip/hip_bf16.h>
#include <math.h>
#include <stdint.h>

// ---- problem constants ----
#define B_    4
#define S_    2048
#define D_    768
#define H_    8
#define HD_   96
#define EXPD_ 3072
#define MSZ   8192   // B*S

#define QSCALE 0.14724439f   // HD^-0.5 * log2(e), folded into Q at QKV epilogue
#define M0_    12.0f         // fixed softmax exponent offset

typedef __bf16 bf16;
typedef __bf16 bf16x4 __attribute__((ext_vector_type(4)));
typedef __bf16 bf16x8 __attribute__((ext_vector_type(8)));
typedef float  f32x4  __attribute__((ext_vector_type(4)));
typedef float  f32x16 __attribute__((ext_vector_type(16)));

typedef __attribute__((address_space(1))) const uint32_t gu32;
typedef __attribute__((address_space(3))) uint32_t lu32;

__device__ __forceinline__ void async_copy16(const void* g, void* l) {
    __builtin_amdgcn_global_load_lds((gu32*)g, (lu32*)l, 16, 0, 0);
}

template<int N> __device__ __forceinline__ void vm_wait() {
    if constexpr (N == 0)      asm volatile("s_waitcnt vmcnt(0)" ::: "memory");
    else if constexpr (N == 3) asm volatile("s_waitcnt vmcnt(3)" ::: "memory");
    else if constexpr (N == 4) asm volatile("s_waitcnt vmcnt(4)" ::: "memory");
    else static_assert(N == 0 || N == 3 || N == 4, "unsupported vmcnt");
}

// GELU (tanh form), computed via exp2: tanh(z) = (e^2z - 1)/(e^2z + 1)
// => gelu = x - x/(e^2z + 1).  Algebraically identical to the tanhf form
// but ~9 VALU ops vs the ~16-op OCML tanhf; saturates correctly at both
// tails (x - 0 = x for z >> 0; x - x = 0 for z << 0) with no inf*0.
__device__ __forceinline__ float gelu_f(float x) {
    float x3 = x * x * x;
    float z  = 0.7978845608028654f * (x + 0.044715f * x3);
    float t  = exp2f(2.8853900817779268f * z);   // e^{2z}
    return x - x / (t + 1.0f);
}

// Runtime dtype sniff: f32 buffer read as bf16 at even indices yields random
// exponents -> some |v|>=1e3 among 64 samples w.p. ~1. bf16 weights never trip.
__device__ __forceinline__ bool sniff_f32(const void* p) {
    const bf16* pb = (const bf16*)p;
    float v = (float)pb[2 * (threadIdx.x & 63)];
    bool big = !(fabsf(v) < 1000.0f);
    return __any(big) != 0;
}

__device__ __forceinline__ float dynld(const void* p, size_t i, bool f32in) {
    return f32in ? ((const float*)p)[i] : (float)((const bf16*)p)[i];
}

// Transpose 64x64 tile helper
__device__ __forceinline__ void transpose_tile(
    const void* __restrict__ src, bf16* __restrict__ dst, int R, int C,
    int r0, int c0, bool f32in)
{
    __shared__ bf16 t[64][65];
    const int tx = threadIdx.x & 63, ty = threadIdx.x >> 6;
#pragma unroll
    for (int i = 0; i < 16; ++i) {
        int rr = ty + i * 4;
        t[rr][tx] = (bf16)dynld(src, (size_t)(r0 + rr) * C + c0 + tx, f32in);
    }
    __syncthreads();
#pragma unroll
    for (int i = 0; i < 16; ++i) {
        int cc = ty + i * 4;
        dst[(size_t)(c0 + cc) * R + r0 + tx] = t[tx][cc];
    }
}

// Merged prep (R14 order fix): work is scheduled mlpT FIRST (tier3, 1296
// blocks), then cast x->bf16 (nCast blocks), then Wq/Wk/Wv -> qkvT LAST
// (432 blocks).  Blocks dispatch roughly in id order, so the L2's freshest
// contents when the QKV GEMM launches are exactly its inputs (xb + qkvT
// ~= 16 MB < 32 MB L2); mlpT (10.6 MB, not needed until the Wo GEMM)
// takes the eviction instead.  R14's mlpT-last order cost QKV ~+13us
// (95us, FETCH 30.9MB) via this pollution -- same mechanism as R8.
__global__ __launch_bounds__(256) void prep_kernel(
    const void* __restrict__ x, bf16* __restrict__ xb, int nCast,
    const void* __restrict__ Wq, const void* __restrict__ Wk, const void* __restrict__ Wv,
    bf16* __restrict__ qkvT,
    const void* __restrict__ Wo, const void* __restrict__ W1, const void* __restrict__ W2,
    bf16* __restrict__ mlpT, int nMlp)
{
    int id = blockIdx.x;
    if (id < nMlp) {
        const void* src; int R, C, r, c; size_t off;
        if (id < 144)      { src = Wo; R = D_;    C = D_;    off = 0;
                             r = id / 12;          c = id % 12; }
        else if (id < 720) { src = W1; R = D_;    C = EXPD_; off = (size_t)D_ * D_;
                             int i = id - 144;     r = i / 48; c = i % 48; }
        else               { src = W2; R = EXPD_; C = D_;    off = (size_t)D_ * D_ + (size_t)D_ * EXPD_;
                             int i = id - 720;     r = i / 12; c = i % 12; }
        const bool f32in = sniff_f32(src);
        transpose_tile(src, mlpT + off, R, C, r * 64, c * 64, f32in);
        return;
    }
    id -= nMlp;
    if (id < nCast) {
        const bool f32in = sniff_f32(x);
        size_t i = ((size_t)id * 256 + threadIdx.x) * 8;
        if (f32in) {
            f32x4 a = *(const f32x4*)((const float*)x + i);
            f32x4 b = *(const f32x4*)((const float*)x + i + 4);
            bf16x8 r;
#pragma unroll
            for (int e = 0; e < 4; ++e) { r[e] = (bf16)a[e]; r[e + 4] = (bf16)b[e]; }
            *(bf16x8*)(xb + i) = r;
        } else {
            *(bf16x8*)(xb + i) = *(const bf16x8*)((const bf16*)x + i);
        }
        return;
    }
    id -= nCast;
    {
        int z = id / 144, rem = id - z * 144;
        const void* src = z == 0 ? Wq : (z == 1 ? Wk : Wv);
        const bool f32in = sniff_f32(src);
        transpose_tile(src, qkvT + (size_t)z * D_ * D_, D_, D_,
                       (rem / 12) * 64, (rem % 12) * 64, f32in);
    }
}

#define MODE_QKV  0   // fused QKV: Q(*QSCALE),K -> [bh][S][HD]; V -> [bh][HD][S]
#define MODE_RES  1   // out bf16 = c + bias(if boff>=0) + res
#define MODE_GELU 2   // out bf16 = gelu(c + bias)

// 32x32x16-MFMA GEMM.  v6: 1-BARRIER-PER-STEP (T3-min template).
// BK=32 double-buffer, one vmcnt(0)+barrier per step (staging is
// L2-resident -> the drain is near-free), T2 XOR swizzle, setprio around
// the MFMA cluster.  16 KB/buffer (BN=128) -> 32 KB LDS -> 5 blocks/CU.
// Loop: stage(t+1) early; compute(t); vmcnt(0); s_barrier.
// Hazards: stage(t) drained by prev iter's vmcnt(0)+barrier before any
// wave's ds_read(t); stage(t+1) overwrites the buffer last read at
// compute(t-1), separated by the same barrier.
// C = A(MxK, row-stride lda) @ Bt(NxK, row-stride ldb)^T + bias[boff+n]
// (boff<0: none). Tile 128xBN, 4 waves. K must be a multiple of 64.
// XCD-aware 1-D grid decode (m fastest within per-XCD stripe).
template<int MODE, bool ADYN, bool RESDYN, int BN>
__global__ __launch_bounds__(256) void gemm2_kernel(
    const void* __restrict__ A, const bf16* __restrict__ Bt,
    const void* __restrict__ b0, const void* __restrict__ b1, const void* __restrict__ b2,
    const void* __restrict__ res, bf16* __restrict__ out,
    int M, int N, int K, int lda, int ldb, int boff, int mstripe,
    const void* __restrict__ sniffp)
{
    constexpr int WN   = BN / 2;
    constexpr int NJ32 = WN / 32;
    constexpr int ABUF = 4096;        // A panel: 128x32 el
    constexpr int BBUF = BN * 32;     // B panel: BNx32 el
    constexpr int BUF  = ABUF + BBUF;
    __shared__ __align__(16) bf16 Sh[2 * BUF];   // >= 8192 el for epilogue

    const bool f32in = sniff_f32(sniffp);
    const int tid  = threadIdx.x;
    const int w    = tid >> 6;
    const int lane = tid & 63;
    const int l32  = lane & 31;
    const int kh   = lane >> 5;     // k-half within a 16-wide mfma step
    const int wr   = w >> 1, wc = w & 1;

    // XCD-aware block decode (m-fast within stripe)
    const int lin  = blockIdx.x;
    const int xcd  = lin & 7;
    const int q    = lin >> 3;
    const int nb   = q / mstripe;
    const int mbin = q - nb * mstripe;
    const int m0   = (xcd * mstripe + mbin) * 128;
    const int n0   = nb * BN;

    const int rsub = lane >> 2;
    // swizzled global k-chunk for this lane's staging slot (T2, write side)
    const int cswz = (((lane & 3) ^ ((rsub >> 1) & 3))) * 8;
    // read-side XOR term (row bits 1..2; chunk bases are multiples of 8)
    const int xh   = (l32 >> 1) & 3;

    f32x16 acc[2][NJ32];
#pragma unroll
    for (int i = 0; i < 2; ++i)
#pragma unroll
        for (int j = 0; j < NJ32; ++j)
#pragma unroll
            for (int e = 0; e < 16; ++e) acc[i][j][e] = 0.f;

    const bf16*  Abf = (const bf16*)A;
    const float* Af  = (const float*)A;

    // stage K-tile at element offset k0 into buffer bsel (async bf16 path)
    auto stage = [&](int k0, int bsel) {
        bf16* As = Sh + bsel * BUF;
        bf16* Bs = As + ABUF;
#pragma unroll
        for (int p = 0; p < 2; ++p) {
            int row = p * 64 + w * 16;      // wave-uniform base row
            async_copy16(Abf + (size_t)(m0 + row + rsub) * lda + k0 + cswz,
                         &As[row * 32]);
        }
#pragma unroll
        for (int p = 0; p < BN / 64; ++p) {
            int row = p * 64 + w * 16;
            async_copy16(Bt + (size_t)(n0 + row + rsub) * ldb + k0 + cswz,
                         &Bs[row * 32]);
        }
    };

    // ds_read fragments (swizzled) + clustered MFMA for one K-tile
    auto compute = [&](int bsel) {
        const bf16* As = Sh + bsel * BUF;
        const bf16* Bs = As + ABUF;
        bf16x8 af[2][2], bfv[NJ32][2];
#pragma unroll
        for (int i = 0; i < 2; ++i)
#pragma unroll
            for (int ks = 0; ks < 2; ++ks)
                af[i][ks] = *(const bf16x8*)(&As[(wr * 64 + i * 32 + l32) * 32
                                                + (((ks * 2 + kh) ^ xh) * 8)]);
#pragma unroll
        for (int j = 0; j < NJ32; ++j)
#pragma unroll
            for (int ks = 0; ks < 2; ++ks)
                bfv[j][ks] = *(const bf16x8*)(&Bs[(wc * WN + j * 32 + l32) * 32
                                                  + (((ks * 2 + kh) ^ xh) * 8)]);
        asm volatile("s_waitcnt lgkmcnt(0)" ::: "memory");
        __builtin_amdgcn_sched_barrier(0);
        __builtin_amdgcn_s_setprio(1);
#pragma unroll
        for (int i = 0; i < 2; ++i)
#pragma unroll
            for (int j = 0; j < NJ32; ++j)
#pragma unroll
                for (int ks = 0; ks < 2; ++ks)
                    acc[i][j] = __builtin_amdgcn_mfma_f32_32x32x16_bf16(af[i][ks], bfv[j][ks], acc[i][j], 0, 0, 0);
        __builtin_amdgcn_s_setprio(0);
    };

    const int nk = K >> 5;
    if constexpr (ADYN) {
        // legacy drain loop (f32-A fallback; LDS writes need full drains)
        auto stage_adyn = [&](int k0, int bsel) {
            bf16* As = Sh + bsel * BUF;
            bf16* Bs = As + ABUF;
            if (f32in) {
#pragma unroll
                for (int p = 0; p < 2; ++p) {
                    int row = p * 64 + w * 16 + rsub;
                    const float* sp = Af + (size_t)(m0 + row) * lda + k0 + cswz;
                    f32x4 u0 = *(const f32x4*)sp;
                    f32x4 u1 = *(const f32x4*)(sp + 4);
                    bf16x8 v;
#pragma unroll
                    for (int e = 0; e < 4; ++e) { v[e] = (bf16)u0[e]; v[e + 4] = (bf16)u1[e]; }
                    *(bf16x8*)(&As[row * 32 + (lane & 3) * 8]) = v;
                }
            } else {
#pragma unroll
                for (int p = 0; p < 2; ++p) {
                    int row = p * 64 + w * 16;
                    async_copy16(Abf + (size_t)(m0 + row + rsub) * lda + k0 + cswz,
                                 &As[row * 32]);
                }
            }
#pragma unroll
            for (int p = 0; p < BN / 64; ++p) {
                int row = p * 64 + w * 16;
                async_copy16(Bt + (size_t)(n0 + row + rsub) * ldb + k0 + cswz,
                             &Bs[row * 32]);
            }
        };
        stage_adyn(0, 0);
        __syncthreads();
        for (int t = 0; t < nk; ++t) {
            const int cur = t & 1;
            if (t + 1 < nk) stage_adyn((t + 1) << 5, cur ^ 1);
            compute(cur);
            __syncthreads();
        }
    } else {
        // v6 loop: one vmcnt(0)+barrier per K-step; stage early, drain late
        stage(0, 0);
        vm_wait<0>();
        __builtin_amdgcn_s_barrier();
        for (int t = 0; t < nk; ++t) {
            const int cur = t & 1;
            if (t + 1 < nk) stage((t + 1) << 5, cur ^ 1);
            compute(cur);
            vm_wait<0>();                   // L2-resident loads: near-free
            __builtin_amdgcn_s_barrier();   // frees buf[cur], publishes t+1
        }
    }
    __syncthreads();   // panels free; epilogue reuses Sh

    if constexpr (MODE == MODE_QKV) {
        // epilogue: stage each 64x32 wave-tile in LDS, then emit b128
        // stores -- along hd for Q/K rows, TRANSPOSED along ss for V^T.
        bf16* Cw = Sh + w * 2048;       // per-wave 64 x 32 slice
        const int bb = (m0 + wr * 64) >> 11;   // wave-uniform batch index
#pragma unroll
        for (int j = 0; j < NJ32; ++j) {
            int nbase = n0 + wc * WN + j * 32;      // multiple of 32
            int which = nbase / D_;                 // wave-uniform
            int n2b   = nbase - which * D_;
            int h     = n2b / HD_;                  // wave-uniform (32 | 96)
            int hd0   = n2b - h * HD_;
            const void* bp = which == 0 ? b0 : (which == 1 ? b1 : b2);
            float bval = dynld(bp, n2b + l32, f32in);
            const int bh = bb * H_ + h;
#pragma unroll
            for (int i = 0; i < 2; ++i)
#pragma unroll
                for (int g = 0; g < 16; ++g) {
                    int rr = (g & 3) + 8 * (g >> 2) + 4 * kh;
                    float v = acc[i][j][g] + bval;
                    if (which == 0) v *= QSCALE;
                    Cw[(i * 32 + rr) * 32 + l32] = (bf16)v;
                }
            // same-wave LDS ops are in-order: reads below see all 64 lanes' writes
            if (which < 2) {
                // Q/K: out[(bh*S + ss)*HD + hd], b128 along hd
#pragma unroll
                for (int pass = 0; pass < 4; ++pass) {
                    int row = pass * 16 + (lane >> 2);
                    int c8  = (lane & 3) * 8;
                    bf16x8 cv = *(const bf16x8*)&Cw[row * 32 + c8];
                    int ss = (m0 + wr * 64 + row) & (S_ - 1);
                    size_t dst = (size_t)which * (MSZ * D_) + ((size_t)bh * S_ + ss) * HD_ + hd0 + c8;
                    *(bf16x8*)&out[dst] = cv;
                }
            } else {
                // V^T: out[2*MSZ*D + (bh*HD + hd)*S + ss], b128 along ss.
                int hd  = hd0 + l32;
                int ss0 = (m0 + wr * 64) & (S_ - 1);
                size_t rowb = (size_t)2 * (MSZ * D_) + ((size_t)bh * HD_ + hd) * S_ + ss0 + kh * 32;
#pragma unroll
                for (int oct = 0; oct < 4; ++oct) {
                    bf16x8 cv;
#pragma unroll
                    for (int e = 0; e < 8; ++e)
                        cv[e] = Cw[(kh * 32 + oct * 8 + e) * 32 + l32];
                    *(bf16x8*)&out[rowb + oct * 8] = cv;
                }
            }
        }
    } else {
        // dense epilogue: stage C through LDS, emit b128 loads/stores.
        bf16* Cw = Sh + w * 2048;        // per-wave 64 x 32 slice
        for (int j = 0; j < NJ32; ++j) {
            int nl = n0 + wc * WN + j * 32 + l32;
            float bval = boff >= 0 ? dynld(b0, boff + nl, f32in) : 0.f;
#pragma unroll
            for (int i = 0; i < 2; ++i)
#pragma unroll
                for (int g = 0; g < 16; ++g) {
                    int rr = (g & 3) + 8 * (g >> 2) + 4 * kh;
                    float v = acc[i][j][g] + bval;
                    if constexpr (MODE == MODE_GELU) v = gelu_f(v);
                    Cw[(i * 32 + rr) * 32 + l32] = (bf16)v;
                }
            // same-wave LDS ops are in-order: reads below see the writes above
#pragma unroll
            for (int pass = 0; pass < 4; ++pass) {
                int row = pass * 16 + (lane >> 2);
                int cc  = (lane & 3) * 8;
                bf16x8 cv = *(const bf16x8*)&Cw[row * 32 + cc];
                int m = m0 + wr * 64 + row;
                int n = n0 + wc * WN + j * 32 + cc;
                size_t off = (size_t)m * N + n;
                if constexpr (MODE == MODE_RES) {
                    bf16x8 o;
                    if (RESDYN && f32in) {
                        f32x4 r0 = *(const f32x4*)((const float*)res + off);
                        f32x4 r1 = *(const f32x4*)((const float*)res + off + 4);
#pragma unroll
                        for (int e = 0; e < 4; ++e) {
                            o[e]     = (bf16)((float)cv[e] + r0[e]);
                            o[e + 4] = (bf16)((float)cv[e + 4] + r1[e]);
                        }
                    } else {
                        bf16x8 rv = *(const bf16x8*)((const bf16*)res + off);
#pragma unroll
                        for (int e = 0; e < 8; ++e) o[e] = (bf16)((float)cv[e] + (float)rv[e]);
                    }
                    *(bf16x8*)&out[off] = o;
                } else {
                    *(bf16x8*)&out[off] = cv;
                }
            }
        }
    }
}

// Flash attention v2 + T5 setprio (R11: 88.9 -> 85.1us) + MFMA row-sum
// (R13: 83.5 -> 78.8us, MfmaUtil 25 -> 29.5): softmax denominator l = P.1
// computed as mfma(pf, ones) on the matrix pipe, replacing per-step VALU
// adds + end-of-kernel shuffles; lsacc[qs][r] holds each lane's output
// rows' sums directly (C layout: row=quad*4+r, all cols equal).
// 256 threads (4 waves), Q-tile 128 (32 q-rows/wave as two 16-row
// subtiles), KV-tile 64.  Swapped QK^T (mfma(K,Q) -> S^T frag: lane holds
// q=l16, kv=quad*4+reg) so P packs as bf16x4 -> one ds_write_b64 per
// kv-16-tile; fixed-max offset -M0 folded into the MFMA accumulator init.
// K/V fragments shared across both q-subtiles; next-tile K/V prefetched
// into registers before compute (T14).  Q,K: [bh][S][96]; Vt_g: [bh][96][S].
// grid (B*H, S/128): x = bh -> XCD k owns bh === k (mod 8) -> K/V L2 locality.
__global__ __launch_bounds__(256, 2) void flash_kernel(
    const bf16* __restrict__ Q, const bf16* __restrict__ Kk,
    const bf16* __restrict__ Vt_g, bf16* __restrict__ ctx)
{
    __shared__ __align__(16) bf16 Ks[64][104];
    __shared__ __align__(16) bf16 Vs[96][72];
    __shared__ __align__(16) bf16 Ps[4][32][72];  // per-wave P [q][kv]

    const int tid  = threadIdx.x;
    const int w    = tid >> 6;
    const int lane = tid & 63;
    const int quad = lane >> 4;
    const int l16  = lane & 15;
    const int bh   = blockIdx.x;
    const size_t base = (size_t)bh * S_ * HD_;
    const int q0   = blockIdx.y * 128 + w * 32;

    // Q fragments (B-operand of swapped mfma): qf[qs][ch] = Q[q0+qs*16+l16][ch*32+quad*8..+7]
    bf16x8 qf[2][3];
#pragma unroll
    for (int qs = 0; qs < 2; ++qs)
#pragma unroll
        for (int ch = 0; ch < 3; ++ch)
            qf[qs][ch] = *(const bf16x8*)(Q + base + (size_t)(q0 + qs * 16 + l16) * HD_ + ch * 32 + quad * 8);

    f32x4 oacc[2][6];
#pragma unroll
    for (int qs = 0; qs < 2; ++qs)
#pragma unroll
        for (int c = 0; c < 6; ++c) oacc[qs][c] = (f32x4){0.f, 0.f, 0.f, 0.f};
    // row-sum accumulators (MFMA with ones B-operand); lsacc[qs][r] ends up
    // holding sum_kv P[q0+qs*16+quad*4+r][kv] in every lane of column l16.
    f32x4 lsacc[2];
    lsacc[0] = (f32x4){0.f, 0.f, 0.f, 0.f};
    lsacc[1] = (f32x4){0.f, 0.f, 0.f, 0.f};
    bf16x8 onesf;
#pragma unroll
    for (int e = 0; e < 8; ++e) onesf[e] = (bf16)1.0f;

    // staging maps: 256 threads x 3 chunks cover K (64x96) and V^T (96x64)
    int krow[3], kc8[3], vrow[3], vc8[3];
#pragma unroll
    for (int i = 0; i < 3; ++i) {
        int id = tid + i * 256;
        krow[i] = id / 12; kc8[i] = (id - krow[i] * 12) * 8;
        vrow[i] = id >> 3; vc8[i] = (id & 7) * 8;
    }

    bf16x8 kreg[3], vreg[3];
    // prologue: stage kv0 = 0
#pragma unroll
    for (int i = 0; i < 3; ++i) {
        kreg[i] = *(const bf16x8*)(Kk + base + (size_t)krow[i] * HD_ + kc8[i]);
        vreg[i] = *(const bf16x8*)(Vt_g + base + (size_t)vrow[i] * S_ + vc8[i]);
    }
#pragma unroll
    for (int i = 0; i < 3; ++i) {
        *(bf16x8*)(&Ks[krow[i]][kc8[i]]) = kreg[i];
        *(bf16x8*)(&Vs[vrow[i]][vc8[i]]) = vreg[i];
    }
    __syncthreads();

    for (int kv0 = 0; kv0 < S_; kv0 += 64) {
        const bool more = (kv0 + 64) < S_;
        if (more) {
            // issue next tile's loads now (T14): latency hides under compute
#pragma unroll
            for (int i = 0; i < 3; ++i) {
                kreg[i] = *(const bf16x8*)(Kk + base + (size_t)(kv0 + 64 + krow[i]) * HD_ + kc8[i]);
                vreg[i] = *(const bf16x8*)(Vt_g + base + (size_t)vrow[i] * S_ + kv0 + 64 + vc8[i]);
            }
        }

        // S^T = K (Q*QSCALE)^T, acc pre-loaded with -M0 (folds exponent offset)
        f32x4 sacc[2][4];
#pragma unroll
        for (int qs = 0; qs < 2; ++qs)
#pragma unroll
            for (int t = 0; t < 4; ++t)
                sacc[qs][t] = (f32x4){-M0_, -M0_, -M0_, -M0_};
        __builtin_amdgcn_s_setprio(1);
#pragma unroll
        for (int t = 0; t < 4; ++t)
#pragma unroll
            for (int ch = 0; ch < 3; ++ch) {
                bf16x8 kf = *(const bf16x8*)(&Ks[t * 16 + l16][ch * 32 + quad * 8]);
                sacc[0][t] = __builtin_amdgcn_mfma_f32_16x16x32_bf16(kf, qf[0][ch], sacc[0][t], 0, 0, 0);
                sacc[1][t] = __builtin_amdgcn_mfma_f32_16x16x32_bf16(kf, qf[1][ch], sacc[1][t], 0, 0, 0);
            }
        __builtin_amdgcn_s_setprio(0);

        // softmax: p = 2^sacc; lane holds q=l16, kv=t*16+quad*4+r -> packed b64 row writes
#pragma unroll
        for (int qs = 0; qs < 2; ++qs) {
            bf16* prow = &Ps[w][qs * 16 + l16][quad * 4];
#pragma unroll
            for (int t = 0; t < 4; ++t) {
                bf16x4 pv;
                pv[0] = (bf16)exp2f(sacc[qs][t][0]);
                pv[1] = (bf16)exp2f(sacc[qs][t][1]);
                pv[2] = (bf16)exp2f(sacc[qs][t][2]);
                pv[3] = (bf16)exp2f(sacc[qs][t][3]);
                *(bf16x4*)(prow + t * 16) = pv;
            }
        }
        // no barrier: Ps is per-wave (in-wave lgkmcnt ordering suffices)

        bf16x8 pf[2][2];
#pragma unroll
        for (int qs = 0; qs < 2; ++qs) {
            pf[qs][0] = *(const bf16x8*)(&Ps[w][qs * 16 + l16][quad * 8]);
            pf[qs][1] = *(const bf16x8*)(&Ps[w][qs * 16 + l16][32 + quad * 8]);
        }
        __builtin_amdgcn_s_setprio(1);
#pragma unroll
        for (int c = 0; c < 6; ++c) {
            bf16x8 vf0 = *(const bf16x8*)(&Vs[c * 16 + l16][quad * 8]);
            bf16x8 vf1 = *(const bf16x8*)(&Vs[c * 16 + l16][32 + quad * 8]);
            oacc[0][c] = __builtin_amdgcn_mfma_f32_16x16x32_bf16(pf[0][0], vf0, oacc[0][c], 0, 0, 0);
            oacc[0][c] = __builtin_amdgcn_mfma_f32_16x16x32_bf16(pf[0][1], vf1, oacc[0][c], 0, 0, 0);
            oacc[1][c] = __builtin_amdgcn_mfma_f32_16x16x32_bf16(pf[1][0], vf0, oacc[1][c], 0, 0, 0);
            oacc[1][c] = __builtin_amdgcn_mfma_f32_16x16x32_bf16(pf[1][1], vf1, oacc[1][c], 0, 0, 0);
        }
        // row-sums via the matrix pipe: l += P . 1
        lsacc[0] = __builtin_amdgcn_mfma_f32_16x16x32_bf16(pf[0][0], onesf, lsacc[0], 0, 0, 0);
        lsacc[0] = __builtin_amdgcn_mfma_f32_16x16x32_bf16(pf[0][1], onesf, lsacc[0], 0, 0, 0);
        lsacc[1] = __builtin_amdgcn_mfma_f32_16x16x32_bf16(pf[1][0], onesf, lsacc[1], 0, 0, 0);
        lsacc[1] = __builtin_amdgcn_mfma_f32_16x16x32_bf16(pf[1][1], onesf, lsacc[1], 0, 0, 0);
        __builtin_amdgcn_s_setprio(0);

        if (more) {
            __syncthreads();            // all waves done reading Ks/Vs
#pragma unroll
            for (int i = 0; i < 3; ++i) {
                *(bf16x8*)(&Ks[krow[i]][kc8[i]]) = kreg[i];
                *(bf16x8*)(&Vs[vrow[i]][vc8[i]]) = vreg[i];
            }
            __syncthreads();            // next tile visible
        }
    }

    // lsacc[qs][r] already holds this lane's output rows' sums (C layout:
    // row = quad*4+r, all columns equal) -- no cross-lane reduce needed.
    const int b = bh >> 3, h = bh & 7;
#pragma unroll
    for (int qs = 0; qs < 2; ++qs)
#pragma unroll
        for (int r = 0; r < 4; ++r) {
            float inv = 1.0f / lsacc[qs][r];
            int srow = q0 + qs * 16 + quad * 4 + r;
            size_t rowbase = ((size_t)b * S_ + srow) * D_ + h * HD_;
#pragma unroll
            for (int c = 0; c < 6; ++c)
                ctx[rowbase + c * 16 + l16] = (bf16)(oacc[qs][c][r] * inv);
        }
}

// LayerNorm over D=768: one wave per row (12 el/lane, bf16x4 vector I/O).
template<bool OUTDYN>
__global__ __launch_bounds__(256) void ln_kernel(
    const bf16* __restrict__ in, const void* __restrict__ g, const void* __restrict__ be,
    void* __restrict__ out, const void* __restrict__ sniffp)
{
    const bool f32in = sniff_f32(sniffp);
    const int w = threadIdx.x >> 6, lane = threadIdx.x & 63;
    const int row = blockIdx.x * 4 + w;
    const size_t rbase = (size_t)row * D_ + lane * 12;

    float v[12];
#pragma unroll
    for (int j = 0; j < 3; ++j) {
        bf16x4 t = *(const bf16x4*)(in + rbase + j * 4);
#pragma unroll
        for (int e = 0; e < 4; ++e) v[j * 4 + e] = (float)t[e];
    }
    float sum = 0.f;
#pragma unroll
    for (int j = 0; j < 12; ++j) sum += v[j];
#pragma unroll
    for (int off = 1; off < 64; off <<= 1) sum += __shfl_xor(sum, off);
    float mu = sum * (1.0f / D_);
    float sq = 0.f;
#pragma unroll
    for (int j = 0; j < 12; ++j) { v[j] -= mu; sq += v[j] * v[j]; }
#pragma unroll
    for (int off = 1; off < 64; off <<= 1) sq += __shfl_xor(sq, off);
    float rstd = rsqrtf(sq * (1.0f / D_) + 1e-5f);

    if (OUTDYN && f32in) {
        float* op = (float*)out + rbase;
#pragma unroll
        for (int j = 0; j < 3; ++j) {
            f32x4 t;
#pragma unroll
            for (int e = 0; e < 4; ++e) {
                int c = lane * 12 + j * 4 + e;
                t[e] = v[j * 4 + e] * rstd * dynld(g, c, true) + dynld(be, c, true);
            }
            *(f32x4*)(op + j * 4) = t;
        }
    } else {
        bf16* op = (bf16*)out + rbase;
#pragma unroll
        for (int j = 0; j < 3; ++j) {
            bf16x4 t;
#pragma unroll
            for (int e = 0; e < 4; ++e) {
                int c = lane * 12 + j * 4 + e;
                t[e] = (bf16)(v[j * 4 + e] * rstd * dynld(g, c, f32in) + dynld(be, c, f32in));
            }
            *(bf16x4*)(op + j * 4) = t;
        }
    }
}

// Wo/W1/W2 -> WoT|W1T|W2T (fallback for tier<3; tier3 uses prep_kernel)
__global__ __launch_bounds__(256) void transpose_mlp_kernel(
    const void* __restrict__ s0, const void* __restrict__ s1, const void* __restrict__ s2,
    bf16* __restrict__ dst)
{
    int id = blockIdx.x;
    const void* src;
    int R, C, r, c;
    size_t off;
    if (id < 144)      { src = s0; R = D_;    C = D_;    off = 0;
                         r = id / 12;          c = id % 12; }
    else if (id < 720) { src = s1; R = D_;    C = EXPD_; off = (size_t)D_ * D_;
                         int i = id - 144;     r = i / 48; c = i % 48; }
    else               { src = s2; R = EXPD_; C = D_;    off = (size_t)D_ * D_ + (size_t)D_ * EXPD_;
                         int i = id - 720;     r = i / 12; c = i % 12; }
    const bool f32in = sniff_f32(src);
    transpose_tile(src, dst + off, R, C, r * 64, c * 64, f32in);
}

extern "C" void kernel_launch(void* const* d_in, const int* in_sizes, int n_in,
                              void* d_out, int out_size, void* d_ws, size_t ws_size,
                              hipStream_t stream)
{
    (void)in_sizes; (void)n_in; (void)out_size;
    const void* x   = d_in[0];
    const void* Wq  = d_in[1];
    const void* bq  = d_in[2];
    const void* Wk  = d_in[3];
    const void* bk  = d_in[4];
    const void* Wv  = d_in[5];
    const void* bv  = d_in[6];
    const void* Wo  = d_in[7];
    const void* bo  = d_in[8];
    const void* g1  = d_in[9];
    const void* be1 = d_in[10];
    const void* W1  = d_in[11];
    const void* bf1 = d_in[12];
    const void* W2  = d_in[13];
    const void* bf2 = d_in[14];
    const void* g2  = d_in[15];
    const void* be2 = d_in[16];

    const size_t REG = (size_t)MSZ * D_ * 2;  // 12.58 MB
    char* p = (char*)d_ws;
    bf16* R0 = (bf16*)p;             // Q     -> x1
    bf16* R1 = (bf16*)(p + REG);     // K     (tier<3: -> WoT|W1T|W2T)
    bf16* R2 = (bf16*)(p + 2 * REG); // V^T   (tier3: -> y1) / nsplit: hb / tier0: y2
    bf16* R3 = (bf16*)(p + 3 * REG); // tier3: mlpT (from prep) | tier<3: y1 -> ...
    bf16* R4 = (bf16*)(p + 4 * REG); // hb (tier3, 4 REG); xb (tier1); nsplit: -> y2

    // tiers: 3 = 9 REG (h at p+4..8, xb at p+8) | 1 = 5 REG (nsplit) | 0 = 4 REG
    int tier = 0;
    if      (ws_size >= 9 * REG) tier = 3;
    else if (ws_size >= 5 * REG) tier = 1;
    bf16* xb = tier == 3 ? (bf16*)(p + 8 * REG) : R4;

    bf16* qkvT = (bf16*)d_out;       // WqT|WkT|WvT (3.54 MB) before flash
    bf16* ctx  = (bf16*)d_out;
    dim3 blk(256);
    const int MB8 = MSZ / 128 / 8;   // mstripe for full-M GEMMs = 8
    const int nCast = tier >= 1 ? MSZ * D_ / (256 * 8) : 0;
    const int nMlp  = tier == 3 ? 1296 : 0;

    // 0) merged prep, scheduled mlpT-first / qkvT-last (L2: QKV inputs
    //    freshest when the QKV GEMM starts; mlpT takes the eviction)
    bf16* mlpT = tier == 3 ? R3 : R1;
    prep_kernel<<<dim3(nMlp + nCast + 432), blk, 0, stream>>>(
        x, xb, nCast, Wq, Wk, Wv, qkvT, Wo, W1, W2, mlpT, nMlp);

    // 1) fused QKV GEMM -> Q*QSCALE(R0), K(R1), V^T(R2).  grid 64x18 = 1152
    if (tier >= 1)
        gemm2_kernel<MODE_QKV, false, false, 128><<<dim3(64 * 18), blk, 0, stream>>>(
            xb, qkvT, bq, bk, bv, nullptr, R0, MSZ, 2304, D_, D_, D_, 0, MB8, Wq);
    else
        gemm2_kernel<MODE_QKV, true, false, 128><<<dim3(64 * 18), blk, 0, stream>>>(
            x, qkvT, bq, bk, bv, nullptr, R0, MSZ, 2304, D_, D_, D_, 0, MB8, Wq);

    // 2) flash attention -> ctx (d_out; qkvT dead). grid x = bh (XCD locality).
    flash_kernel<<<dim3(B_ * H_, S_ / 128), dim3(256), 0, stream>>>(R0, R1, R2, ctx);

    // 2b) tier<3: transpose Wo/W1/W2 into R1 (K dead)
    if (tier != 3)
        transpose_mlp_kernel<<<dim3(1296), blk, 0, stream>>>(Wo, W1, W2, mlpT);

    bf16* WoT = mlpT;
    bf16* W1T = WoT + (size_t)D_ * D_;
    bf16* W2T = W1T + (size_t)D_ * EXPD_;

    // 3) y1 = ctx@Wo + bo + x.  tier3: -> R2 (V^T dead); tier<3: -> R3
    bf16* y1b = tier == 3 ? R2 : R3;
    if (tier >= 1)
        gemm2_kernel<MODE_RES, false, false, 64><<<dim3(64 * 12), blk, 0, stream>>>(
            ctx, WoT, bo, nullptr, nullptr, xb, y1b, MSZ, D_, D_, D_, D_, 0, MB8, Wq);
    else
        gemm2_kernel<MODE_RES, false, true, 64><<<dim3(64 * 12), blk, 0, stream>>>(
            ctx, WoT, bo, nullptr, nullptr, x, y1b, MSZ, D_, D_, D_, D_, 0, MB8, Wq);

    // 4) x1 = LN1(y1) -> R0 (Q dead)
    bf16* x1b = R0;
    ln_kernel<false><<<dim3(MSZ / 4), blk, 0, stream>>>(y1b, g1, be1, x1b, Wq);

    // 5/6) FFN -> y2
    bf16* y2b;
    if (tier == 3) {
        // full h (4 REG at p+4..8); y2 -> xb slot (R8; xb dead after y1)
        bf16* hb = R4;
        y2b = xb;
        gemm2_kernel<MODE_GELU, false, false, 128><<<dim3(64 * 24), blk, 0, stream>>>(
            x1b, W1T, bf1, nullptr, nullptr, nullptr, hb, MSZ, EXPD_, D_, D_, D_, 0, MB8, Wq);
        gemm2_kernel<MODE_RES, false, false, 64><<<dim3(64 * 12), blk, 0, stream>>>(
            hb, W2T, bf2, nullptr, nullptr, x1b, y2b, MSZ, D_, EXPD_, EXPD_, EXPD_, 0, MB8, Wq);
    } else if (tier == 1) {
        // N-split halves in hb = R2|R3 (V, y1 dead; hb contiguous stride 1536); y2 -> R4
        bf16* hb = R2;
        y2b = R4;
        gemm2_kernel<MODE_GELU, false, false, 128><<<dim3(64 * 12), blk, 0, stream>>>(
            x1b, W1T, bf1, nullptr, nullptr, nullptr, hb, MSZ, 1536, D_, D_, D_, 0, MB8, Wq);
        gemm2_kernel<MODE_RES, false, false, 64><<<dim3(64 * 12), blk, 0, stream>>>(
            hb, W2T, bf2, nullptr, nullptr, x1b, y2b, MSZ, D_, 1536, 1536, EXPD_, 0, MB8, Wq);
        gemm2_kernel<MODE_GELU, false, false, 128><<<dim3(64 * 12), blk, 0, stream>>>(
            x1b, W1T + (size_t)1536 * D_, bf1, nullptr, nullptr, nullptr, hb, MSZ, 1536, D_, D_, D_, 1536, MB8, Wq);
        gemm2_kernel<MODE_RES, false, false, 64><<<dim3(64 * 12), blk, 0, stream>>>(
            hb, W2T + 1536, nullptr, nullptr, nullptr, y2b, y2b, MSZ, D_, 1536, 1536, EXPD_, -1, MB8, Wq);
    } else {
        // 4-REG fallback: M-chunked FFN (hb = R3 after y1 consumed; y2 -> R2, V dead)
        bf16* hb = R3;
        y2b = R2;
        const int CH = 2048;   // 16 m-blocks -> mstripe 2
        for (int c0 = 0; c0 < MSZ; c0 += CH) {
            const bf16* x1c = x1b + (size_t)c0 * D_;
            gemm2_kernel<MODE_GELU, false, false, 128><<<dim3(16 * 24), blk, 0, stream>>>(
                x1c, W1T, bf1, nullptr, nullptr, nullptr, hb, CH, EXPD_, D_, D_, D_, 0, 2, Wq);
            gemm2_kernel<MODE_RES, false, false, 64><<<dim3(16 * 12), blk, 0, stream>>>(
                hb, W2T, bf2, nullptr, nullptr, x1c, y2b + (size_t)c0 * D_, CH, D_, EXPD_, EXPD_, EXPD_, 0, 2, Wq);
        }
    }

    // 7) out = LN2(y2) -> d_out
    ln_kernel<true><<<dim3(MSZ / 4), blk, 0, stream>>>(y2b, g2, be2, d_out, Wq);
}